// Round 11
// baseline (429.978 us; speedup 1.0000x reference)
//
#include <hip/hip_runtime.h>

#define NEG_INF_F (-1.0e9f)

typedef _Float16 f16x8 __attribute__((ext_vector_type(8)));
typedef float f32x4 __attribute__((ext_vector_type(4)));

__device__ inline unsigned short f16_of(float f) {
    _Float16 h = (_Float16)f;
    return __builtin_bit_cast(unsigned short, h);
}
__device__ inline float f32_of(unsigned short u) {
    return (float)__builtin_bit_cast(_Float16, u);
}

// async global->LDS, 16B per lane; LDS dest = wave-uniform base + lane*16
__device__ inline void gload16(const unsigned short* g, unsigned short* l) {
    __builtin_amdgcn_global_load_lds(
        (const __attribute__((address_space(1))) unsigned int*)g,
        (__attribute__((address_space(3))) unsigned int*)l, 16, 0, 0);
}

// [R][32]-f16 tile, chunk swizzle ^((r>>1)&3)
__device__ inline f16x8 frag32(const unsigned short* t, int r, int ch) {
    return *reinterpret_cast<const f16x8*>(&t[r * 32 + (ch ^ ((r >> 1) & 3)) * 8]);
}

// Stage a 256x32 f16 tile: 2 gloads per wave.
__device__ inline void stage_256x32(const unsigned short* __restrict__ g0, int ldg, int k0,
                                    unsigned short* qbuf, int w, int lane) {
#pragma unroll
    for (int c = 0; c < 2; ++c) {
        const int r = c * 128 + w * 16 + (lane >> 2);
        const int co = ((lane & 3) ^ ((r >> 1) & 3)) * 8;
        gload16(g0 + (long long)r * ldg + k0 + co, qbuf + (c * 128 + w * 16) * 32);
    }
}
// Stage a 128x32 f16 tile: 1 gload per wave.
__device__ inline void stage_128x32(const unsigned short* __restrict__ g0, int ldg, int k0,
                                    unsigned short* qbuf, int w, int lane) {
    const int r = w * 16 + (lane >> 2);
    const int co = ((lane & 3) ^ ((r >> 1) & 3)) * 8;
    gload16(g0 + (long long)r * ldg + k0 + co, qbuf + (w * 16) * 32);
}

// ---------------- 8-wave double-buffered GEMM (f16), 64KB LDS = 2 blocks/CU ----
// C = A * B^T.
// TERMS: 2 = A split (Ah*B + Al*B): tile 128x256, BK=32, buf {Ah@0,Al@4096,B@8192};
//        1 = single A,B: tile 256x256, BK=32, buf {A@0,B@8192}.
// OMODE: 0 = f32 C (+ optional NEG_INF*mask[col]); 1 = split f16 (Ch,Cl);
//        2 = plain f16 (Ch); 3 = f16 transposed V^T store Ch[b2][col][s].
template <int TERMS, int OMODE>
__global__ __launch_bounds__(512, 2) void mfma_gemm256(
    const unsigned short* __restrict__ Ah_g, const unsigned short* __restrict__ Al_g,
    long long strideA, int lda,
    const unsigned short* __restrict__ Bh_g,
    long long strideB, int ldb,
    float* __restrict__ Cf, unsigned short* __restrict__ Ch, unsigned short* __restrict__ Cl,
    long long strideC, int ldc, int K,
    const int* __restrict__ mask, long long strideMask)
{
    constexpr int BUF = 16384;  // ushorts = 32KB per buffer
    const int b = blockIdx.z;
    const int tid = threadIdx.x;
    const int w = tid >> 6, lane = tid & 63;
    const int lr = lane & 15, lg = lane >> 4;
    const int rowBase = blockIdx.x * ((TERMS == 2) ? 128 : 256);
    const int colBase = blockIdx.y * 256;

    // TERMS=2: 2 row-groups(64) x 4 col-groups(64); TERMS=1: 2 row-groups(128) x 4 col-groups(64)
    const int wr = w & 1;
    const int wc = w >> 1;

    __shared__ unsigned short smem[32768];  // 64 KB: 2 x 32KB buffers

    const unsigned short* Ah0 = Ah_g + (long long)b * strideA + (long long)rowBase * lda;
    const unsigned short* Bh0 = Bh_g + (long long)b * strideB + (long long)colBase * ldb;
    const unsigned short* Al0 = (TERMS == 2)
        ? Al_g + (long long)b * strideA + (long long)rowBase * lda : nullptr;

    f32x4 acc[(TERMS == 2) ? 4 : 8][4] = {};
    const int NT = K / 32;

    // stage tile 0
    if constexpr (TERMS == 2) {
        stage_128x32(Ah0, lda, 0, smem, w, lane);
        stage_128x32(Al0, lda, 0, smem + 4096, w, lane);
        stage_256x32(Bh0, ldb, 0, smem + 8192, w, lane);
    } else {
        stage_256x32(Ah0, lda, 0, smem, w, lane);
        stage_256x32(Bh0, ldb, 0, smem + 8192, w, lane);
    }
    __syncthreads();

    for (int kt = 0; kt < NT; ++kt) {
        const unsigned short* cbuf = smem + (kt & 1) * BUF;
        if (kt + 1 < NT) {
            unsigned short* nbuf = smem + ((kt + 1) & 1) * BUF;
            const int k1 = (kt + 1) * 32;
            if constexpr (TERMS == 2) {
                stage_128x32(Ah0, lda, k1, nbuf, w, lane);
                stage_128x32(Al0, lda, k1, nbuf + 4096, w, lane);
                stage_256x32(Bh0, ldb, k1, nbuf + 8192, w, lane);
            } else {
                stage_256x32(Ah0, lda, k1, nbuf, w, lane);
                stage_256x32(Bh0, ldb, k1, nbuf + 8192, w, lane);
            }
        }

        if constexpr (TERMS == 2) {
            const unsigned short* tAh = cbuf;
            const unsigned short* tAl = cbuf + 4096;
            const unsigned short* tB  = cbuf + 8192;
            f16x8 ah[4], al[4], bh[4];
#pragma unroll
            for (int i = 0; i < 4; ++i) {
                const int r = wr * 64 + i * 16 + lr;
                ah[i] = frag32(tAh, r, lg);
                al[i] = frag32(tAl, r, lg);
            }
#pragma unroll
            for (int j = 0; j < 4; ++j)
                bh[j] = frag32(tB, wc * 64 + j * 16 + lr, lg);
#pragma unroll
            for (int i = 0; i < 4; ++i)
#pragma unroll
                for (int j = 0; j < 4; ++j) {
                    f32x4 a = acc[i][j];
                    a = __builtin_amdgcn_mfma_f32_16x16x32_f16(ah[i], bh[j], a, 0, 0, 0);
                    a = __builtin_amdgcn_mfma_f32_16x16x32_f16(al[i], bh[j], a, 0, 0, 0);
                    acc[i][j] = a;
                }
        } else {
            const unsigned short* tA = cbuf;
            const unsigned short* tB = cbuf + 8192;
            f16x8 bh[4];
#pragma unroll
            for (int j = 0; j < 4; ++j)
                bh[j] = frag32(tB, wc * 64 + j * 16 + lr, lg);
#pragma unroll
            for (int rf = 0; rf < 8; ++rf) {
                const f16x8 ah = frag32(tA, wr * 128 + rf * 16 + lr, lg);
#pragma unroll
                for (int j = 0; j < 4; ++j)
                    acc[rf][j] = __builtin_amdgcn_mfma_f32_16x16x32_f16(ah, bh[j], acc[rf][j], 0, 0, 0);
            }
        }
        __syncthreads();
    }

    // ---- epilogue: per-wave private LDS bounce (8KB each) ----
    __syncthreads();
    float* stg = reinterpret_cast<float*>(smem) + w * 2048;
    const int colg0 = colBase + wc * 64;
    constexpr int NR = (TERMS == 2) ? 2 : 4;   // rounds of 32 rows x 64 cols

#pragma unroll
    for (int rnd = 0; rnd < NR; ++rnd) {
        const int rowg0 = rowBase + ((TERMS == 2) ? (wr * 64) : (wr * 128)) + rnd * 32;
#pragma unroll
        for (int ii = 0; ii < 2; ++ii)
#pragma unroll
            for (int j = 0; j < 4; ++j)
#pragma unroll
                for (int r2 = 0; r2 < 4; ++r2)
                    stg[(ii * 16 + lg * 4 + r2) * 64 + j * 16 + lr] = acc[rnd * 2 + ii][j][r2];

        if constexpr (OMODE == 0) {
#pragma unroll
            for (int t = 0; t < 8; ++t) {
                const int idx = t * 256 + lane * 4;
                const int r = idx >> 6, c = idx & 63;
                float4 v = *reinterpret_cast<const float4*>(&stg[idx]);
                const int colg = colg0 + c;
                if (mask != nullptr) {
                    const int4 mv = *reinterpret_cast<const int4*>(
                        &mask[(long long)b * strideMask + colg]);
                    v.x += NEG_INF_F * (float)mv.x;
                    v.y += NEG_INF_F * (float)mv.y;
                    v.z += NEG_INF_F * (float)mv.z;
                    v.w += NEG_INF_F * (float)mv.w;
                }
                *reinterpret_cast<float4*>(
                    &Cf[(long long)b * strideC + (long long)(rowg0 + r) * ldc + colg]) = v;
            }
        } else if constexpr (OMODE == 1) {
#pragma unroll
            for (int t = 0; t < 8; ++t) {
                const int idx = t * 256 + lane * 4;
                const int r = idx >> 6, c = idx & 63;
                const float4 v = *reinterpret_cast<const float4*>(&stg[idx]);
                ushort4 h, l;
                h.x = f16_of(v.x); l.x = f16_of(v.x - f32_of(h.x));
                h.y = f16_of(v.y); l.y = f16_of(v.y - f32_of(h.y));
                h.z = f16_of(v.z); l.z = f16_of(v.z - f32_of(h.z));
                h.w = f16_of(v.w); l.w = f16_of(v.w - f32_of(h.w));
                const long long cidx = (long long)(rowg0 + r) * ldc + colg0 + c;
                *reinterpret_cast<ushort4*>(&Ch[cidx]) = h;
                *reinterpret_cast<ushort4*>(&Cl[cidx]) = l;
            }
        } else if constexpr (OMODE == 2) {
#pragma unroll
            for (int t = 0; t < 8; ++t) {
                const int idx = t * 256 + lane * 4;
                const int r = idx >> 6, c = idx & 63;
                const float4 v = *reinterpret_cast<const float4*>(&stg[idx]);
                ushort4 h;
                h.x = f16_of(v.x); h.y = f16_of(v.y);
                h.z = f16_of(v.z); h.w = f16_of(v.w);
                *reinterpret_cast<ushort4*>(
                    &Ch[(long long)(rowg0 + r) * ldc + colg0 + c]) = h;
            }
        } else {  // OMODE == 3: V^T store  Ch[b2][col][s]
            const int b2 = rowg0 >> 11;
            const int s0 = rowg0 & 2047;
            const int colg = colg0 + lane;
            alignas(16) unsigned short u[32];
#pragma unroll
            for (int rr = 0; rr < 32; ++rr) u[rr] = f16_of(stg[rr * 64 + lane]);
            unsigned short* vp = Ch + (long long)b2 * (1024LL * 2048)
                               + (long long)colg * 2048 + s0;
#pragma unroll
            for (int q = 0; q < 4; ++q)
                *reinterpret_cast<uint4*>(vp + q * 8) =
                    *reinterpret_cast<const uint4*>(&u[q * 8]);
        }
        __syncthreads();
    }
}

// ---------------- helpers ----------------
// f32 -> (hi, lo) f16 split
__global__ __launch_bounds__(256) void split2_kernel(
    const float* __restrict__ in, unsigned short* __restrict__ hi,
    unsigned short* __restrict__ lo, long long n)
{
    for (long long i = ((long long)blockIdx.x * 256 + threadIdx.x) * 4; i < n;
         i += (long long)gridDim.x * 256 * 4) {
        float4 v = *reinterpret_cast<const float4*>(&in[i]);
        ushort4 h, l;
        h.x = f16_of(v.x); l.x = f16_of(v.x - f32_of(h.x));
        h.y = f16_of(v.y); l.y = f16_of(v.y - f32_of(h.y));
        h.z = f16_of(v.z); l.z = f16_of(v.z - f32_of(h.z));
        h.w = f16_of(v.w); l.w = f16_of(v.w - f32_of(h.w));
        *reinterpret_cast<ushort4*>(&hi[i]) = h;
        *reinterpret_cast<ushort4*>(&lo[i]) = l;
    }
}

// f32 [N][N] -> TRANSPOSED hi/lo f16: hi[j][i] = split(in[i][j]).  N % 64 == 0.
__global__ __launch_bounds__(256) void tsplit_kernel(
    const float* __restrict__ in, unsigned short* __restrict__ hi,
    unsigned short* __restrict__ lo, int N)
{
    __shared__ float tile[64][65];
    const int bi = blockIdx.x * 64;
    const int bj = blockIdx.y * 64;
    const int t = threadIdx.x;
    const int c4 = (t & 15) * 4;
    const int r0 = (t >> 4) * 4;
#pragma unroll
    for (int rr = 0; rr < 4; ++rr) {
        float4 v = *reinterpret_cast<const float4*>(
            &in[(long long)(bi + r0 + rr) * N + bj + c4]);
        tile[r0 + rr][c4 + 0] = v.x;
        tile[r0 + rr][c4 + 1] = v.y;
        tile[r0 + rr][c4 + 2] = v.z;
        tile[r0 + rr][c4 + 3] = v.w;
    }
    __syncthreads();
    const int oc  = t >> 2;
    const int or0 = (t & 3) * 16;
    alignas(16) unsigned short uh[16], ul[16];
#pragma unroll
    for (int e = 0; e < 16; ++e) {
        const float f = tile[or0 + e][oc];
        const unsigned short h = f16_of(f);
        uh[e] = h;
        ul[e] = f16_of(f - f32_of(h));
    }
    unsigned short* hp = hi + (long long)(bj + oc) * N + bi + or0;
    unsigned short* lp = lo + (long long)(bj + oc) * N + bi + or0;
    *reinterpret_cast<uint4*>(hp)     = *reinterpret_cast<const uint4*>(&uh[0]);
    *reinterpret_cast<uint4*>(hp + 8) = *reinterpret_cast<const uint4*>(&uh[8]);
    *reinterpret_cast<uint4*>(lp)     = *reinterpret_cast<const uint4*>(&ul[0]);
    *reinterpret_cast<uint4*>(lp + 8) = *reinterpret_cast<const uint4*>(&ul[8]);
}

// f32 -> f16
__global__ __launch_bounds__(256) void cvt_kernel(
    const float* __restrict__ in, unsigned short* __restrict__ out, long long n)
{
    for (long long i = ((long long)blockIdx.x * 256 + threadIdx.x) * 4; i < n;
         i += (long long)gridDim.x * 256 * 4) {
        float4 v = *reinterpret_cast<const float4*>(&in[i]);
        ushort4 h;
        h.x = f16_of(v.x); h.y = f16_of(v.y); h.z = f16_of(v.z); h.w = f16_of(v.w);
        *reinterpret_cast<ushort4*>(&out[i]) = h;
    }
}

// In-place f32 row softmax (rows=16384, cols=2048) + f16 copy for PV.
__global__ __launch_bounds__(256) void softmax_kernel(
    float* __restrict__ s, unsigned short* __restrict__ p)
{
    const long long row = blockIdx.x;
    float* sp = s + row * 2048;
    const int tid = threadIdx.x;

    float v[8];
    *reinterpret_cast<float4*>(&v[0]) = *reinterpret_cast<const float4*>(&sp[tid * 8]);
    *reinterpret_cast<float4*>(&v[4]) = *reinterpret_cast<const float4*>(&sp[tid * 8 + 4]);

    float m = v[0];
#pragma unroll
    for (int i = 1; i < 8; ++i) m = fmaxf(m, v[i]);
#pragma unroll
    for (int off = 1; off < 64; off <<= 1) m = fmaxf(m, __shfl_xor(m, off));

    __shared__ float redm[4];
    __shared__ float reds[4];
    if ((tid & 63) == 0) redm[tid >> 6] = m;
    __syncthreads();
    m = fmaxf(fmaxf(redm[0], redm[1]), fmaxf(redm[2], redm[3]));

    float sum = 0.f;
#pragma unroll
    for (int i = 0; i < 8; ++i) {
        v[i] = __expf(v[i] - m);
        sum += v[i];
    }
#pragma unroll
    for (int off = 1; off < 64; off <<= 1) sum += __shfl_xor(sum, off);
    if ((tid & 63) == 0) reds[tid >> 6] = sum;
    __syncthreads();
    sum = reds[0] + reds[1] + reds[2] + reds[3];

    const float inv = 1.0f / sum;
#pragma unroll
    for (int i = 0; i < 8; ++i) v[i] *= inv;

    *reinterpret_cast<float4*>(&sp[tid * 8])     = *reinterpret_cast<const float4*>(&v[0]);
    *reinterpret_cast<float4*>(&sp[tid * 8 + 4]) = *reinterpret_cast<const float4*>(&v[4]);

    ushort4 o0, o1;
    o0.x = f16_of(v[0]); o0.y = f16_of(v[1]); o0.z = f16_of(v[2]); o0.w = f16_of(v[3]);
    o1.x = f16_of(v[4]); o1.y = f16_of(v[5]); o1.z = f16_of(v[6]); o1.w = f16_of(v[7]);
    *reinterpret_cast<ushort4*>(&p[row * 2048 + tid * 8])     = o0;
    *reinterpret_cast<ushort4*>(&p[row * 2048 + tid * 8 + 4]) = o1;
}

extern "C" void kernel_launch(void* const* d_in, const int* in_sizes, int n_in,
                              void* d_out, int out_size, void* d_ws, size_t ws_size,
                              hipStream_t stream)
{
    (void)in_sizes; (void)n_in; (void)out_size; (void)ws_size;

    const int S = 2048, D = 1024;
    const long long BS  = 8LL * S;          // 16384
    const long long SD  = (long long)S * D;
    const long long SS  = (long long)S * S;
    const long long BSD = BS * D;
    const long long DD  = (long long)D * D;

    const float* x    = (const float*)d_in[0];
    const int*   mask = (const int*)d_in[1];
    const float* wq   = (const float*)d_in[2];
    const float* wk   = (const float*)d_in[3];
    const float* wv   = (const float*)d_in[4];

    float* out = (float*)d_out;             // [BS, D] f32 (final)
    float* s   = out + BSD;                 // [B, S, S] f32 (final)

    // ws layout (halves):
    //   Gh [16384][1024] | Gl [16384][1024]   (later overwritten by p [B][S][S])
    //   Vt [B][D][S] | wvh | Mth
    unsigned short* Gh  = (unsigned short*)d_ws;
    unsigned short* Gl  = Gh + BSD;
    unsigned short* p   = Gh;               // 2*BSD halves, overwrites Gh+Gl
    unsigned short* Vt  = Gh + 2 * BSD;
    unsigned short* wvh = Gh + 3 * BSD;
    unsigned short* Mth = wvh + DD;

    // x split lives in d_out's out-region until PV overwrites it
    unsigned short* xh = (unsigned short*)out;
    unsigned short* xl = xh + BSD;
    // transposed weight splits live in d_out's s-region until scores overwrites it
    unsigned short* wqTh = (unsigned short*)s;   // [1024][1024] = wq^T hi
    unsigned short* wqTl = wqTh + DD;
    unsigned short* wkTh = wqTl + DD;
    unsigned short* wkTl = wkTh + DD;

    dim3 blk256(256), blk512(512);

    split2_kernel<<<dim3(2048), blk256, 0, stream>>>(x, xh, xl, BSD);
    tsplit_kernel<<<dim3(16, 16), blk256, 0, stream>>>(wq, wqTh, wqTl, D);
    tsplit_kernel<<<dim3(16, 16), blk256, 0, stream>>>(wk, wkTh, wkTl, D);

    // Mt[j][i] = sum_e wk[e][j]*wq[e][i]; A = (wkTh,wkTl) split, B = wqTh, plain f16 out
    mfma_gemm256<2, 2><<<dim3(8, 4, 1), blk512, 0, stream>>>(
        wkTh, wkTl, 0, D, wqTh, 0, D,
        nullptr, Mth, nullptr, 0, D, D, nullptr, 0);

    // G = x @ Mt^T: A = (xh,xl) split, B = Mth; split-f16 out (Gh,Gl)
    mfma_gemm256<2, 1><<<dim3(128, 4, 1), blk512, 0, stream>>>(
        xh, xl, 0, D, Mth, 0, D,
        nullptr, Gh, Gl, 0, D, D, nullptr, 0);

    // scores = G @ x^T + NEG_INF*mask: A = (Gh,Gl) split, B = xh; f32 out
    mfma_gemm256<2, 0><<<dim3(16, 8, 8), blk512, 0, stream>>>(
        Gh, Gl, SD, D, xh, SD, D,
        s, nullptr, nullptr, SS, S, D, mask, S);

    // softmax in place + f16 p for PV (p overwrites Gh/Gl)
    softmax_kernel<<<dim3(16384), blk256, 0, stream>>>(s, p);

    // wv -> f16, then V^T = (x @ wv^T)^T directly (1-term, transposed store)
    cvt_kernel<<<dim3(512), blk256, 0, stream>>>(wv, wvh, DD);
    mfma_gemm256<1, 3><<<dim3(64, 4, 1), blk512, 0, stream>>>(
        xh, nullptr, 0, D, wvh, 0, D,
        nullptr, Vt, nullptr, 0, 0, D, nullptr, 0);

    // out = p @ V = p @ (V^T)^T  (1-term BK=32, NT form, f32 out)
    mfma_gemm256<1, 0><<<dim3(8, 4, 8), blk512, 0, stream>>>(
        p, nullptr, SS, S, Vt, SD, S,
        out, nullptr, nullptr, SD, D, S, nullptr, 0);
}

// Round 12
// 429.728 us; speedup vs baseline: 1.0006x; 1.0006x over previous
//
#include <hip/hip_runtime.h>

#define NEG_INF_F (-1.0e9f)

typedef _Float16 f16x8 __attribute__((ext_vector_type(8)));
typedef float f32x4 __attribute__((ext_vector_type(4)));

__device__ inline unsigned short f16_of(float f) {
    _Float16 h = (_Float16)f;
    return __builtin_bit_cast(unsigned short, h);
}
__device__ inline float f32_of(unsigned short u) {
    return (float)__builtin_bit_cast(_Float16, u);
}

// async global->LDS, 16B per lane; LDS dest = wave-uniform base + lane*16
__device__ inline void gload16(const unsigned short* g, unsigned short* l) {
    __builtin_amdgcn_global_load_lds(
        (const __attribute__((address_space(1))) unsigned int*)g,
        (__attribute__((address_space(3))) unsigned int*)l, 16, 0, 0);
}

// [R][32]-f16 tile, chunk swizzle ^((r>>1)&3)
__device__ inline f16x8 frag32(const unsigned short* t, int r, int ch) {
    return *reinterpret_cast<const f16x8*>(&t[r * 32 + (ch ^ ((r >> 1) & 3)) * 8]);
}
// [R][64]-f16 tile, chunk swizzle ^(r&7)
__device__ inline f16x8 frag64(const unsigned short* t, int r, int ch) {
    return *reinterpret_cast<const f16x8*>(&t[r * 64 + (ch ^ (r & 7)) * 8]);
}

// Stage a 256x32 f16 tile: 2 gloads per wave.
__device__ inline void stage_256x32(const unsigned short* __restrict__ g0, int ldg, int k0,
                                    unsigned short* qbuf, int w, int lane) {
#pragma unroll
    for (int c = 0; c < 2; ++c) {
        const int r = c * 128 + w * 16 + (lane >> 2);
        const int co = ((lane & 3) ^ ((r >> 1) & 3)) * 8;
        gload16(g0 + (long long)r * ldg + k0 + co, qbuf + (c * 128 + w * 16) * 32);
    }
}

#define VMW4() asm volatile("s_waitcnt vmcnt(4)" ::: "memory")
#define VMW0() asm volatile("s_waitcnt vmcnt(0)" ::: "memory")
#define LGKM0() asm volatile("s_waitcnt lgkmcnt(0)" ::: "memory")
#define SCHB0() __builtin_amdgcn_sched_barrier(0)
#define BARR() __builtin_amdgcn_s_barrier()

// ============ 8-phase (4 phases/K-tile) TERMS-2 GEMM: C = (Ah+Al) * B^T ======
// Tile 256x256, BK=32, 8 waves (2 row x 4 col), wave tile 128x64, acc[8][4].
// LDS: 2 x 48KB buffers {Ah@0, Al@8192, B@16384 (ushorts)}.
// Per K-tile: 4 phases x 16 MFMA; stage units (2 gloads each) rotate into
// just-consumed regions; boundary wait = counted vmcnt(4) (never drains).
// OMODE: 0 = f32 C + NEG_INF*mask[col]; 1 = split f16 (Ch,Cl); 2 = plain f16.
template <int OMODE>
__global__ __launch_bounds__(512, 1) void gemm8ph(
    const unsigned short* __restrict__ Ah_g, const unsigned short* __restrict__ Al_g,
    long long strideA, int lda,
    const unsigned short* __restrict__ Bh_g,
    long long strideB, int ldb,
    float* __restrict__ Cf, unsigned short* __restrict__ Ch, unsigned short* __restrict__ Cl,
    long long strideC, int ldc, int K,
    const int* __restrict__ mask, long long strideMask)
{
    constexpr int BUF = 24576;  // ushorts = 48KB
    const int b = blockIdx.z;
    const int tid = threadIdx.x;
    const int w = tid >> 6, lane = tid & 63;
    const int wr = w >> 2, wc = w & 3;
    const int lr = lane & 15, lg = lane >> 4;
    const int rowBase = blockIdx.x * 256;
    const int colBase = blockIdx.y * 256;

    __shared__ unsigned short smem[49152];  // 96 KB

    const unsigned short* Ah0 = Ah_g + (long long)b * strideA + (long long)rowBase * lda;
    const unsigned short* Al0 = Al_g + (long long)b * strideA + (long long)rowBase * lda;
    const unsigned short* Bh0 = Bh_g + (long long)b * strideB + (long long)colBase * ldb;

    f32x4 acc[8][4] = {};
    const int NT = K / 32;

    // prologue: U(0,Ah) U(0,Al) U(0,B) U(1,B) U(1,Ah)  (10 loads/wave)
    stage_256x32(Ah0, lda, 0, smem + 0,     w, lane);
    stage_256x32(Al0, lda, 0, smem + 8192,  w, lane);
    stage_256x32(Bh0, ldb, 0, smem + 16384, w, lane);
    stage_256x32(Bh0, ldb, 32, smem + BUF + 16384, w, lane);
    stage_256x32(Ah0, lda, 32, smem + BUF + 0,     w, lane);
    VMW4();   // tile-0 units (6 oldest loads) complete; 4 younger in flight
    BARR();

    for (int t = 0; t < NT; ++t) {
        const unsigned short* cb = smem + (t & 1) * BUF;
        unsigned short* cbm = smem + (t & 1) * BUF;          // t+2 staging target
        unsigned short* nb  = smem + ((t + 1) & 1) * BUF;    // t+1 buffer
        const unsigned short* tAh = cb;
        const unsigned short* tAl = cb + 8192;
        const unsigned short* tB  = cb + 16384;
        f16x8 bfrag[4], afr[4];

        // ---- phase 1: ah[0..3] x b ----
#pragma unroll
        for (int j = 0; j < 4; ++j) bfrag[j] = frag32(tB, wc * 64 + j * 16 + lr, lg);
#pragma unroll
        for (int i = 0; i < 4; ++i) afr[i] = frag32(tAh, wr * 128 + i * 16 + lr, lg);
        if (t + 1 < NT) stage_256x32(Al0, lda, (t + 1) * 32, nb + 8192, w, lane);
        BARR(); LGKM0(); SCHB0();
        __builtin_amdgcn_s_setprio(1);
#pragma unroll
        for (int i = 0; i < 4; ++i)
#pragma unroll
            for (int j = 0; j < 4; ++j)
                acc[i][j] = __builtin_amdgcn_mfma_f32_16x16x32_f16(afr[i], bfrag[j], acc[i][j], 0, 0, 0);
        __builtin_amdgcn_s_setprio(0);
        BARR();

        // ---- phase 2: ah[4..7] x b ----
#pragma unroll
        for (int i = 0; i < 4; ++i) afr[i] = frag32(tAh, wr * 128 + 64 + i * 16 + lr, lg);
        if (t + 2 < NT) stage_256x32(Bh0, ldb, (t + 2) * 32, cbm + 16384, w, lane);
        BARR(); LGKM0(); SCHB0();
        __builtin_amdgcn_s_setprio(1);
#pragma unroll
        for (int i = 0; i < 4; ++i)
#pragma unroll
            for (int j = 0; j < 4; ++j)
                acc[4 + i][j] = __builtin_amdgcn_mfma_f32_16x16x32_f16(afr[i], bfrag[j], acc[4 + i][j], 0, 0, 0);
        __builtin_amdgcn_s_setprio(0);
        BARR();

        // ---- phase 3: al[0..3] x b ----
#pragma unroll
        for (int i = 0; i < 4; ++i) afr[i] = frag32(tAl, wr * 128 + i * 16 + lr, lg);
        if (t + 2 < NT) stage_256x32(Ah0, lda, (t + 2) * 32, cbm + 0, w, lane);
        BARR(); LGKM0(); SCHB0();
        __builtin_amdgcn_s_setprio(1);
#pragma unroll
        for (int i = 0; i < 4; ++i)
#pragma unroll
            for (int j = 0; j < 4; ++j)
                acc[i][j] = __builtin_amdgcn_mfma_f32_16x16x32_f16(afr[i], bfrag[j], acc[i][j], 0, 0, 0);
        __builtin_amdgcn_s_setprio(0);
        BARR();

        // ---- phase 4: al[4..7] x b ----
#pragma unroll
        for (int i = 0; i < 4; ++i) afr[i] = frag32(tAl, wr * 128 + 64 + i * 16 + lr, lg);
        BARR(); LGKM0(); SCHB0();
        __builtin_amdgcn_s_setprio(1);
#pragma unroll
        for (int i = 0; i < 4; ++i)
#pragma unroll
            for (int j = 0; j < 4; ++j)
                acc[4 + i][j] = __builtin_amdgcn_mfma_f32_16x16x32_f16(afr[i], bfrag[j], acc[4 + i][j], 0, 0, 0);
        __builtin_amdgcn_s_setprio(0);
        // boundary: tile t+1's units done; t+2's 4 loads stay in flight
        if (t + 2 < NT)      { VMW4(); }
        else if (t + 1 < NT) { VMW0(); }
        BARR();
    }

    // ---- epilogue: per-wave private LDS bounce (8KB each), 4 rounds 32x64 ----
    __syncthreads();
    float* stg = reinterpret_cast<float*>(smem) + w * 2048;
    const int colg0 = colBase + wc * 64;
#pragma unroll
    for (int rnd = 0; rnd < 4; ++rnd) {
        const int rowg0 = rowBase + wr * 128 + rnd * 32;
#pragma unroll
        for (int ii = 0; ii < 2; ++ii)
#pragma unroll
            for (int j = 0; j < 4; ++j)
#pragma unroll
                for (int r2 = 0; r2 < 4; ++r2)
                    stg[(ii * 16 + lg * 4 + r2) * 64 + j * 16 + lr] = acc[rnd * 2 + ii][j][r2];

        if constexpr (OMODE == 0) {
#pragma unroll
            for (int t = 0; t < 8; ++t) {
                const int idx = t * 256 + lane * 4;
                const int r = idx >> 6, c = idx & 63;
                float4 v = *reinterpret_cast<const float4*>(&stg[idx]);
                const int colg = colg0 + c;
                if (mask != nullptr) {
                    const int4 mv = *reinterpret_cast<const int4*>(
                        &mask[(long long)b * strideMask + colg]);
                    v.x += NEG_INF_F * (float)mv.x;
                    v.y += NEG_INF_F * (float)mv.y;
                    v.z += NEG_INF_F * (float)mv.z;
                    v.w += NEG_INF_F * (float)mv.w;
                }
                *reinterpret_cast<float4*>(
                    &Cf[(long long)b * strideC + (long long)(rowg0 + r) * ldc + colg]) = v;
            }
        } else if constexpr (OMODE == 1) {
#pragma unroll
            for (int t = 0; t < 8; ++t) {
                const int idx = t * 256 + lane * 4;
                const int r = idx >> 6, c = idx & 63;
                const float4 v = *reinterpret_cast<const float4*>(&stg[idx]);
                ushort4 h, l;
                h.x = f16_of(v.x); l.x = f16_of(v.x - f32_of(h.x));
                h.y = f16_of(v.y); l.y = f16_of(v.y - f32_of(h.y));
                h.z = f16_of(v.z); l.z = f16_of(v.z - f32_of(h.z));
                h.w = f16_of(v.w); l.w = f16_of(v.w - f32_of(h.w));
                const long long cidx = (long long)(rowg0 + r) * ldc + colg0 + c;
                *reinterpret_cast<ushort4*>(&Ch[cidx]) = h;
                *reinterpret_cast<ushort4*>(&Cl[cidx]) = l;
            }
        } else {
#pragma unroll
            for (int t = 0; t < 8; ++t) {
                const int idx = t * 256 + lane * 4;
                const int r = idx >> 6, c = idx & 63;
                const float4 v = *reinterpret_cast<const float4*>(&stg[idx]);
                ushort4 h;
                h.x = f16_of(v.x); h.y = f16_of(v.y);
                h.z = f16_of(v.z); h.w = f16_of(v.w);
                *reinterpret_cast<ushort4*>(
                    &Ch[(long long)(rowg0 + r) * ldc + colg0 + c]) = h;
            }
        }
        __syncthreads();
    }
}

// ---------------- r10 TERMS=1 kernel (Vproj, PV) ----------------
__device__ inline void stage_ktile1(
    const unsigned short* __restrict__ Ah0, int lda,
    const unsigned short* __restrict__ Bh0, int ldb,
    int k0, unsigned short* buf, int w, int lane)
{
#pragma unroll
    for (int c = 0; c < 4; ++c) {
        const int r = c * 64 + w * 8 + (lane >> 3);
        const int co = ((lane & 7) ^ (r & 7)) * 8;
        const int lb = (c * 64 + w * 8) * 64;
        gload16(Ah0 + (long long)r * lda + k0 + co, buf + lb);
        gload16(Bh0 + (long long)r * ldb + k0 + co, buf + 16384 + lb);
    }
}

// 256x256, BK=64, 8 waves (2 row x 4 col). OMODE: 0 = f32 C; 3 = V^T store.
template <int OMODE>
__global__ __launch_bounds__(512, 2) void mfma_gemm1(
    const unsigned short* __restrict__ Ah_g, long long strideA, int lda,
    const unsigned short* __restrict__ Bh_g, long long strideB, int ldb,
    float* __restrict__ Cf, unsigned short* __restrict__ Ch,
    long long strideC, int ldc, int K)
{
    const int b = blockIdx.z;
    const int tid = threadIdx.x;
    const int w = tid >> 6, lane = tid & 63;
    const int wr = w >> 2, wc = w & 3;
    const int lr = lane & 15, lg = lane >> 4;
    const int rowBase = blockIdx.x * 256;
    const int colBase = blockIdx.y * 256;

    __shared__ unsigned short smem[65536];  // 128 KB: 2 x 64KB

    const unsigned short* Ah0 = Ah_g + (long long)b * strideA + (long long)rowBase * lda;
    const unsigned short* Bh0 = Bh_g + (long long)b * strideB + (long long)colBase * ldb;

    f32x4 acc[8][4] = {};
    const int NT = K / 64;

    stage_ktile1(Ah0, lda, Bh0, ldb, 0, smem, w, lane);
    __syncthreads();

    for (int kt = 0; kt < NT; ++kt) {
        const unsigned short* cbuf = smem + (kt & 1) * 32768;
        if (kt + 1 < NT)
            stage_ktile1(Ah0, lda, Bh0, ldb, (kt + 1) * 64,
                         smem + ((kt + 1) & 1) * 32768, w, lane);

        const unsigned short* tA = cbuf;
        const unsigned short* tB = cbuf + 16384;
        f16x8 bh[8];
#pragma unroll
        for (int j = 0; j < 4; ++j)
#pragma unroll
            for (int ks = 0; ks < 2; ++ks)
                bh[j * 2 + ks] = frag64(tB, wc * 64 + j * 16 + lr, ks * 4 + lg);
#pragma unroll
        for (int ih = 0; ih < 2; ++ih) {
            f16x8 ah[8];
#pragma unroll
            for (int f = 0; f < 4; ++f)
#pragma unroll
                for (int ks = 0; ks < 2; ++ks)
                    ah[f * 2 + ks] = frag64(tA, wr * 128 + ih * 64 + f * 16 + lr, ks * 4 + lg);
#pragma unroll
            for (int f = 0; f < 4; ++f)
#pragma unroll
                for (int j = 0; j < 4; ++j) {
                    f32x4 a = acc[ih * 4 + f][j];
                    a = __builtin_amdgcn_mfma_f32_16x16x32_f16(ah[f * 2 + 0], bh[j * 2 + 0], a, 0, 0, 0);
                    a = __builtin_amdgcn_mfma_f32_16x16x32_f16(ah[f * 2 + 1], bh[j * 2 + 1], a, 0, 0, 0);
                    acc[ih * 4 + f][j] = a;
                }
        }
        __syncthreads();
    }

    __syncthreads();
    float* stg = reinterpret_cast<float*>(smem) + w * 2048;
    const int colg0 = colBase + wc * 64;
#pragma unroll
    for (int rnd = 0; rnd < 4; ++rnd) {
        const int rowg0 = rowBase + wr * 128 + rnd * 32;
#pragma unroll
        for (int ii = 0; ii < 2; ++ii)
#pragma unroll
            for (int j = 0; j < 4; ++j)
#pragma unroll
                for (int r2 = 0; r2 < 4; ++r2)
                    stg[(ii * 16 + lg * 4 + r2) * 64 + j * 16 + lr] = acc[rnd * 2 + ii][j][r2];

        if constexpr (OMODE == 0) {
#pragma unroll
            for (int t = 0; t < 8; ++t) {
                const int idx = t * 256 + lane * 4;
                const int r = idx >> 6, c = idx & 63;
                const float4 v = *reinterpret_cast<const float4*>(&stg[idx]);
                *reinterpret_cast<float4*>(
                    &Cf[(long long)b * strideC + (long long)(rowg0 + r) * ldc + colg0 + c]) = v;
            }
        } else {  // OMODE == 3: V^T store  Ch[b2][col][s]
            const int b2 = rowg0 >> 11;
            const int s0 = rowg0 & 2047;
            const int colg = colg0 + lane;
            alignas(16) unsigned short u[32];
#pragma unroll
            for (int rr = 0; rr < 32; ++rr) u[rr] = f16_of(stg[rr * 64 + lane]);
            unsigned short* vp = Ch + (long long)b2 * (1024LL * 2048)
                               + (long long)colg * 2048 + s0;
#pragma unroll
            for (int q = 0; q < 4; ++q)
                *reinterpret_cast<uint4*>(vp + q * 8) =
                    *reinterpret_cast<const uint4*>(&u[q * 8]);
        }
        __syncthreads();
    }
}

// ---------------- helpers ----------------
__global__ __launch_bounds__(256) void split2_kernel(
    const float* __restrict__ in, unsigned short* __restrict__ hi,
    unsigned short* __restrict__ lo, long long n)
{
    for (long long i = ((long long)blockIdx.x * 256 + threadIdx.x) * 4; i < n;
         i += (long long)gridDim.x * 256 * 4) {
        float4 v = *reinterpret_cast<const float4*>(&in[i]);
        ushort4 h, l;
        h.x = f16_of(v.x); l.x = f16_of(v.x - f32_of(h.x));
        h.y = f16_of(v.y); l.y = f16_of(v.y - f32_of(h.y));
        h.z = f16_of(v.z); l.z = f16_of(v.z - f32_of(h.z));
        h.w = f16_of(v.w); l.w = f16_of(v.w - f32_of(h.w));
        *reinterpret_cast<ushort4*>(&hi[i]) = h;
        *reinterpret_cast<ushort4*>(&lo[i]) = l;
    }
}

__global__ __launch_bounds__(256) void tsplit_kernel(
    const float* __restrict__ in, unsigned short* __restrict__ hi,
    unsigned short* __restrict__ lo, int N)
{
    __shared__ float tile[64][65];
    const int bi = blockIdx.x * 64;
    const int bj = blockIdx.y * 64;
    const int t = threadIdx.x;
    const int c4 = (t & 15) * 4;
    const int r0 = (t >> 4) * 4;
#pragma unroll
    for (int rr = 0; rr < 4; ++rr) {
        float4 v = *reinterpret_cast<const float4*>(
            &in[(long long)(bi + r0 + rr) * N + bj + c4]);
        tile[r0 + rr][c4 + 0] = v.x;
        tile[r0 + rr][c4 + 1] = v.y;
        tile[r0 + rr][c4 + 2] = v.z;
        tile[r0 + rr][c4 + 3] = v.w;
    }
    __syncthreads();
    const int oc  = t >> 2;
    const int or0 = (t & 3) * 16;
    alignas(16) unsigned short uh[16], ul[16];
#pragma unroll
    for (int e = 0; e < 16; ++e) {
        const float f = tile[or0 + e][oc];
        const unsigned short h = f16_of(f);
        uh[e] = h;
        ul[e] = f16_of(f - f32_of(h));
    }
    unsigned short* hp = hi + (long long)(bj + oc) * N + bi + or0;
    unsigned short* lp = lo + (long long)(bj + oc) * N + bi + or0;
    *reinterpret_cast<uint4*>(hp)     = *reinterpret_cast<const uint4*>(&uh[0]);
    *reinterpret_cast<uint4*>(hp + 8) = *reinterpret_cast<const uint4*>(&uh[8]);
    *reinterpret_cast<uint4*>(lp)     = *reinterpret_cast<const uint4*>(&ul[0]);
    *reinterpret_cast<uint4*>(lp + 8) = *reinterpret_cast<const uint4*>(&ul[8]);
}

__global__ __launch_bounds__(256) void cvt_kernel(
    const float* __restrict__ in, unsigned short* __restrict__ out, long long n)
{
    for (long long i = ((long long)blockIdx.x * 256 + threadIdx.x) * 4; i < n;
         i += (long long)gridDim.x * 256 * 4) {
        float4 v = *reinterpret_cast<const float4*>(&in[i]);
        ushort4 h;
        h.x = f16_of(v.x); h.y = f16_of(v.y); h.z = f16_of(v.z); h.w = f16_of(v.w);
        *reinterpret_cast<ushort4*>(&out[i]) = h;
    }
}

__global__ __launch_bounds__(256) void softmax_kernel(
    float* __restrict__ s, unsigned short* __restrict__ p)
{
    const long long row = blockIdx.x;
    float* sp = s + row * 2048;
    const int tid = threadIdx.x;

    float v[8];
    *reinterpret_cast<float4*>(&v[0]) = *reinterpret_cast<const float4*>(&sp[tid * 8]);
    *reinterpret_cast<float4*>(&v[4]) = *reinterpret_cast<const float4*>(&sp[tid * 8 + 4]);

    float m = v[0];
#pragma unroll
    for (int i = 1; i < 8; ++i) m = fmaxf(m, v[i]);
#pragma unroll
    for (int off = 1; off < 64; off <<= 1) m = fmaxf(m, __shfl_xor(m, off));

    __shared__ float redm[4];
    __shared__ float reds[4];
    if ((tid & 63) == 0) redm[tid >> 6] = m;
    __syncthreads();
    m = fmaxf(fmaxf(redm[0], redm[1]), fmaxf(redm[2], redm[3]));

    float sum = 0.f;
#pragma unroll
    for (int i = 0; i < 8; ++i) {
        v[i] = __expf(v[i] - m);
        sum += v[i];
    }
#pragma unroll
    for (int off = 1; off < 64; off <<= 1) sum += __shfl_xor(sum, off);
    if ((tid & 63) == 0) reds[tid >> 6] = sum;
    __syncthreads();
    sum = reds[0] + reds[1] + reds[2] + reds[3];

    const float inv = 1.0f / sum;
#pragma unroll
    for (int i = 0; i < 8; ++i) v[i] *= inv;

    *reinterpret_cast<float4*>(&sp[tid * 8])     = *reinterpret_cast<const float4*>(&v[0]);
    *reinterpret_cast<float4*>(&sp[tid * 8 + 4]) = *reinterpret_cast<const float4*>(&v[4]);

    ushort4 o0, o1;
    o0.x = f16_of(v[0]); o0.y = f16_of(v[1]); o0.z = f16_of(v[2]); o0.w = f16_of(v[3]);
    o1.x = f16_of(v[4]); o1.y = f16_of(v[5]); o1.z = f16_of(v[6]); o1.w = f16_of(v[7]);
    *reinterpret_cast<ushort4*>(&p[row * 2048 + tid * 8])     = o0;
    *reinterpret_cast<ushort4*>(&p[row * 2048 + tid * 8 + 4]) = o1;
}

extern "C" void kernel_launch(void* const* d_in, const int* in_sizes, int n_in,
                              void* d_out, int out_size, void* d_ws, size_t ws_size,
                              hipStream_t stream)
{
    (void)in_sizes; (void)n_in; (void)out_size; (void)ws_size;

    const int S = 2048, D = 1024;
    const long long BS  = 8LL * S;          // 16384
    const long long SD  = (long long)S * D;
    const long long SS  = (long long)S * S;
    const long long BSD = BS * D;
    const long long DD  = (long long)D * D;

    const float* x    = (const float*)d_in[0];
    const int*   mask = (const int*)d_in[1];
    const float* wq   = (const float*)d_in[2];
    const float* wk   = (const float*)d_in[3];
    const float* wv   = (const float*)d_in[4];

    float* out = (float*)d_out;             // [BS, D] f32 (final)
    float* s   = out + BSD;                 // [B, S, S] f32 (final)

    // ws layout (halves):
    //   Gh [16384][1024] | Gl [16384][1024]   (later overwritten by p [B][S][S])
    //   Vt [B][D][S] | wvh | Mth
    unsigned short* Gh  = (unsigned short*)d_ws;
    unsigned short* Gl  = Gh + BSD;
    unsigned short* p   = Gh;               // 2*BSD halves, overwrites Gh+Gl
    unsigned short* Vt  = Gh + 2 * BSD;
    unsigned short* wvh = Gh + 3 * BSD;
    unsigned short* Mth = wvh + DD;

    // x split lives in d_out's out-region until PV overwrites it
    unsigned short* xh = (unsigned short*)out;
    unsigned short* xl = xh + BSD;
    // transposed weight splits live in d_out's s-region until scores overwrites it
    unsigned short* wqTh = (unsigned short*)s;   // [1024][1024] = wq^T hi
    unsigned short* wqTl = wqTh + DD;
    unsigned short* wkTh = wqTl + DD;
    unsigned short* wkTl = wkTh + DD;

    dim3 blk256(256), blk512(512);

    split2_kernel<<<dim3(2048), blk256, 0, stream>>>(x, xh, xl, BSD);
    tsplit_kernel<<<dim3(16, 16), blk256, 0, stream>>>(wq, wqTh, wqTl, D);
    tsplit_kernel<<<dim3(16, 16), blk256, 0, stream>>>(wk, wkTh, wkTl, D);

    // Mt[j][i] = sum_e wk[e][j]*wq[e][i]; A = (wkTh,wkTl) split, B = wqTh, plain f16 out
    gemm8ph<2><<<dim3(4, 4, 1), blk512, 0, stream>>>(
        wkTh, wkTl, 0, D, wqTh, 0, D,
        nullptr, Mth, nullptr, 0, D, D, nullptr, 0);

    // G = x @ Mt^T: A = (xh,xl) split, B = Mth; split-f16 out (Gh,Gl)
    gemm8ph<1><<<dim3(64, 4, 1), blk512, 0, stream>>>(
        xh, xl, 0, D, Mth, 0, D,
        nullptr, Gh, Gl, 0, D, D, nullptr, 0);

    // scores = G @ x^T + NEG_INF*mask: A = (Gh,Gl) split, B = xh; f32 out
    gemm8ph<0><<<dim3(8, 8, 8), blk512, 0, stream>>>(
        Gh, Gl, SD, D, xh, SD, D,
        s, nullptr, nullptr, SS, S, D, mask, S);

    // softmax in place + f16 p for PV (p overwrites Gh/Gl)
    softmax_kernel<<<dim3(16384), blk256, 0, stream>>>(s, p);

    // wv -> f16, then V^T = (x @ wv^T)^T directly (1-term, transposed store)
    cvt_kernel<<<dim3(512), blk256, 0, stream>>>(wv, wvh, DD);
    mfma_gemm1<3><<<dim3(64, 4, 1), blk512, 0, stream>>>(
        xh, 0, D, wvh, 0, D, nullptr, Vt, 0, D, D);

    // out = p @ V = p @ (V^T)^T  (1-term BK=64, NT form, f32 out)
    mfma_gemm1<0><<<dim3(8, 4, 8), blk512, 0, stream>>>(
        p, SS, S, Vt, SD, S, out, nullptr, SD, D, S);
}

// Round 13
// 406.296 us; speedup vs baseline: 1.0583x; 1.0577x over previous
//
#include <hip/hip_runtime.h>

#define NEG_INF_F (-1.0e9f)

typedef _Float16 f16x8 __attribute__((ext_vector_type(8)));
typedef float f32x4 __attribute__((ext_vector_type(4)));

__device__ inline unsigned short f16_of(float f) {
    _Float16 h = (_Float16)f;
    return __builtin_bit_cast(unsigned short, h);
}
__device__ inline float f32_of(unsigned short u) {
    return (float)__builtin_bit_cast(_Float16, u);
}

// async global->LDS, 16B per lane; LDS dest = wave-uniform base + lane*16
__device__ inline void gload16(const unsigned short* g, unsigned short* l) {
    __builtin_amdgcn_global_load_lds(
        (const __attribute__((address_space(1))) unsigned int*)g,
        (__attribute__((address_space(3))) unsigned int*)l, 16, 0, 0);
}

// [R][32]-f16 tile, chunk swizzle ^((r>>1)&3)
__device__ inline f16x8 frag32(const unsigned short* t, int r, int ch) {
    return *reinterpret_cast<const f16x8*>(&t[r * 32 + (ch ^ ((r >> 1) & 3)) * 8]);
}
// [R][64]-f16 tile, chunk swizzle ^(r&7)
__device__ inline f16x8 frag64(const unsigned short* t, int r, int ch) {
    return *reinterpret_cast<const f16x8*>(&t[r * 64 + (ch ^ (r & 7)) * 8]);
}

// Stage a 256x32 f16 tile: 2 gloads per wave.
__device__ inline void stage_256x32(const unsigned short* __restrict__ g0, int ldg, int k0,
                                    unsigned short* qbuf, int w, int lane) {
#pragma unroll
    for (int c = 0; c < 2; ++c) {
        const int r = c * 128 + w * 16 + (lane >> 2);
        const int co = ((lane & 3) ^ ((r >> 1) & 3)) * 8;
        gload16(g0 + (long long)r * ldg + k0 + co, qbuf + (c * 128 + w * 16) * 32);
    }
}
// Stage a 128x32 f16 tile: 1 gload per wave.
__device__ inline void stage_128x32(const unsigned short* __restrict__ g0, int ldg, int k0,
                                    unsigned short* qbuf, int w, int lane) {
    const int r = w * 16 + (lane >> 2);
    const int co = ((lane & 3) ^ ((r >> 1) & 3)) * 8;
    gload16(g0 + (long long)r * ldg + k0 + co, qbuf + (w * 16) * 32);
}

// ======== TERMS-2 GEMM: C = (Ah+Al) * B^T.  Tile 128x256, BK=32, 64KB LDS ====
// (2 blocks/CU — best measured scores config, r11.)  8 waves: 2 row-groups(64)
// x 4 col-groups(64), acc[4][4].  XCD-aware block swizzle (grid size % 8 == 0).
// OMODE: 0 = f32 C + NEG_INF*mask[col]; 1 = split f16 (Ch,Cl); 2 = plain f16.
template <int OMODE>
__global__ __launch_bounds__(512, 2) void gemm2(
    const unsigned short* __restrict__ Ah_g, const unsigned short* __restrict__ Al_g,
    long long strideA, int lda,
    const unsigned short* __restrict__ Bh_g, long long strideB, int ldb,
    float* __restrict__ Cf, unsigned short* __restrict__ Ch, unsigned short* __restrict__ Cl,
    long long strideC, int ldc, int K,
    const int* __restrict__ mask, long long strideMask)
{
    constexpr int BUF = 16384;  // ushorts = 32KB per buffer
    // XCD-aware bijective swizzle of the flattened block id
    const int gx = gridDim.x, gy = gridDim.y;
    int bid = blockIdx.x + gx * (blockIdx.y + gy * blockIdx.z);
    const int nwg = gx * gy * gridDim.z;
    bid = (bid & 7) * (nwg >> 3) + (bid >> 3);
    const int bx = bid % gx;
    const int by = (bid / gx) % gy;
    const int b  = bid / (gx * gy);

    const int tid = threadIdx.x;
    const int w = tid >> 6, lane = tid & 63;
    const int wr = w & 1, wc = w >> 1;
    const int lr = lane & 15, lg = lane >> 4;
    const int rowBase = bx * 128;
    const int colBase = by * 256;

    __shared__ unsigned short smem[32768];  // 64 KB: 2 x 32KB buffers

    const unsigned short* Ah0 = Ah_g + (long long)b * strideA + (long long)rowBase * lda;
    const unsigned short* Al0 = Al_g + (long long)b * strideA + (long long)rowBase * lda;
    const unsigned short* Bh0 = Bh_g + (long long)b * strideB + (long long)colBase * ldb;

    f32x4 acc[4][4] = {};
    const int NT = K / 32;

    stage_128x32(Ah0, lda, 0, smem, w, lane);
    stage_128x32(Al0, lda, 0, smem + 4096, w, lane);
    stage_256x32(Bh0, ldb, 0, smem + 8192, w, lane);
    __syncthreads();

    for (int kt = 0; kt < NT; ++kt) {
        const unsigned short* cbuf = smem + (kt & 1) * BUF;
        if (kt + 1 < NT) {
            unsigned short* nbuf = smem + ((kt + 1) & 1) * BUF;
            const int k1 = (kt + 1) * 32;
            stage_128x32(Ah0, lda, k1, nbuf, w, lane);
            stage_128x32(Al0, lda, k1, nbuf + 4096, w, lane);
            stage_256x32(Bh0, ldb, k1, nbuf + 8192, w, lane);
        }
        const unsigned short* tAh = cbuf;
        const unsigned short* tAl = cbuf + 4096;
        const unsigned short* tB  = cbuf + 8192;
        f16x8 ah[4], al[4], bh[4];
#pragma unroll
        for (int i = 0; i < 4; ++i) {
            const int r = wr * 64 + i * 16 + lr;
            ah[i] = frag32(tAh, r, lg);
            al[i] = frag32(tAl, r, lg);
        }
#pragma unroll
        for (int j = 0; j < 4; ++j)
            bh[j] = frag32(tB, wc * 64 + j * 16 + lr, lg);
#pragma unroll
        for (int i = 0; i < 4; ++i)
#pragma unroll
            for (int j = 0; j < 4; ++j) {
                f32x4 a = acc[i][j];
                a = __builtin_amdgcn_mfma_f32_16x16x32_f16(ah[i], bh[j], a, 0, 0, 0);
                a = __builtin_amdgcn_mfma_f32_16x16x32_f16(al[i], bh[j], a, 0, 0, 0);
                acc[i][j] = a;
            }
        __syncthreads();
    }

    // ---- epilogue: per-wave private LDS bounce (8KB each), no interior barriers ----
    __syncthreads();
    float* stg = reinterpret_cast<float*>(smem) + w * 2048;
    const int colg0 = colBase + wc * 64;
#pragma unroll
    for (int rnd = 0; rnd < 2; ++rnd) {
        const int rowg0 = rowBase + wr * 64 + rnd * 32;
#pragma unroll
        for (int ii = 0; ii < 2; ++ii)
#pragma unroll
            for (int j = 0; j < 4; ++j)
#pragma unroll
                for (int r2 = 0; r2 < 4; ++r2)
                    stg[(ii * 16 + lg * 4 + r2) * 64 + j * 16 + lr] = acc[rnd * 2 + ii][j][r2];

        if constexpr (OMODE == 0) {
#pragma unroll
            for (int t = 0; t < 8; ++t) {
                const int idx = t * 256 + lane * 4;
                const int r = idx >> 6, c = idx & 63;
                float4 v = *reinterpret_cast<const float4*>(&stg[idx]);
                const int colg = colg0 + c;
                if (mask != nullptr) {
                    const int4 mv = *reinterpret_cast<const int4*>(
                        &mask[(long long)b * strideMask + colg]);
                    v.x += NEG_INF_F * (float)mv.x;
                    v.y += NEG_INF_F * (float)mv.y;
                    v.z += NEG_INF_F * (float)mv.z;
                    v.w += NEG_INF_F * (float)mv.w;
                }
                *reinterpret_cast<float4*>(
                    &Cf[(long long)b * strideC + (long long)(rowg0 + r) * ldc + colg]) = v;
            }
        } else if constexpr (OMODE == 1) {
#pragma unroll
            for (int t = 0; t < 8; ++t) {
                const int idx = t * 256 + lane * 4;
                const int r = idx >> 6, c = idx & 63;
                const float4 v = *reinterpret_cast<const float4*>(&stg[idx]);
                ushort4 h, l;
                h.x = f16_of(v.x); l.x = f16_of(v.x - f32_of(h.x));
                h.y = f16_of(v.y); l.y = f16_of(v.y - f32_of(h.y));
                h.z = f16_of(v.z); l.z = f16_of(v.z - f32_of(h.z));
                h.w = f16_of(v.w); l.w = f16_of(v.w - f32_of(h.w));
                const long long cidx = (long long)(rowg0 + r) * ldc + colg0 + c;
                *reinterpret_cast<ushort4*>(&Ch[cidx]) = h;
                *reinterpret_cast<ushort4*>(&Cl[cidx]) = l;
            }
        } else {
#pragma unroll
            for (int t = 0; t < 8; ++t) {
                const int idx = t * 256 + lane * 4;
                const int r = idx >> 6, c = idx & 63;
                const float4 v = *reinterpret_cast<const float4*>(&stg[idx]);
                ushort4 h;
                h.x = f16_of(v.x); h.y = f16_of(v.y);
                h.z = f16_of(v.z); h.w = f16_of(v.w);
                *reinterpret_cast<ushort4*>(
                    &Ch[(long long)(rowg0 + r) * ldc + colg0 + c]) = h;
            }
        }
    }
}

// ======== TERMS-1 GEMM (Vproj, PV): 256x256, BK=64, 2-barrier loop ==========
__device__ inline void stage_ktile1(
    const unsigned short* __restrict__ Ah0, int lda,
    const unsigned short* __restrict__ Bh0, int ldb,
    int k0, unsigned short* buf, int w, int lane)
{
#pragma unroll
    for (int c = 0; c < 4; ++c) {
        const int r = c * 64 + w * 8 + (lane >> 3);
        const int co = ((lane & 7) ^ (r & 7)) * 8;
        const int lb = (c * 64 + w * 8) * 64;
        gload16(Ah0 + (long long)r * lda + k0 + co, buf + lb);
        gload16(Bh0 + (long long)r * ldb + k0 + co, buf + 16384 + lb);
    }
}

// OMODE: 0 = f32 C; 3 = f16 transposed V^T store Ch[b2][col][s].
template <int OMODE>
__global__ __launch_bounds__(512, 2) void mfma_gemm1(
    const unsigned short* __restrict__ Ah_g, long long strideA, int lda,
    const unsigned short* __restrict__ Bh_g, long long strideB, int ldb,
    float* __restrict__ Cf, unsigned short* __restrict__ Ch,
    long long strideC, int ldc, int K)
{
    const int b = blockIdx.z;
    const int tid = threadIdx.x;
    const int w = tid >> 6, lane = tid & 63;
    const int wr = w >> 2, wc = w & 3;
    const int lr = lane & 15, lg = lane >> 4;
    const int rowBase = blockIdx.x * 256;
    const int colBase = blockIdx.y * 256;

    __shared__ unsigned short smem[65536];  // 128 KB: 2 x 64KB

    const unsigned short* Ah0 = Ah_g + (long long)b * strideA + (long long)rowBase * lda;
    const unsigned short* Bh0 = Bh_g + (long long)b * strideB + (long long)colBase * ldb;

    f32x4 acc[8][4] = {};
    const int NT = K / 64;

    stage_ktile1(Ah0, lda, Bh0, ldb, 0, smem, w, lane);
    __syncthreads();

    for (int kt = 0; kt < NT; ++kt) {
        const unsigned short* cbuf = smem + (kt & 1) * 32768;
        if (kt + 1 < NT)
            stage_ktile1(Ah0, lda, Bh0, ldb, (kt + 1) * 64,
                         smem + ((kt + 1) & 1) * 32768, w, lane);

        const unsigned short* tA = cbuf;
        const unsigned short* tB = cbuf + 16384;
        f16x8 bh[8];
#pragma unroll
        for (int j = 0; j < 4; ++j)
#pragma unroll
            for (int ks = 0; ks < 2; ++ks)
                bh[j * 2 + ks] = frag64(tB, wc * 64 + j * 16 + lr, ks * 4 + lg);
#pragma unroll
        for (int ih = 0; ih < 2; ++ih) {
            f16x8 ah[8];
#pragma unroll
            for (int f = 0; f < 4; ++f)
#pragma unroll
                for (int ks = 0; ks < 2; ++ks)
                    ah[f * 2 + ks] = frag64(tA, wr * 128 + ih * 64 + f * 16 + lr, ks * 4 + lg);
#pragma unroll
            for (int f = 0; f < 4; ++f)
#pragma unroll
                for (int j = 0; j < 4; ++j) {
                    f32x4 a = acc[ih * 4 + f][j];
                    a = __builtin_amdgcn_mfma_f32_16x16x32_f16(ah[f * 2 + 0], bh[j * 2 + 0], a, 0, 0, 0);
                    a = __builtin_amdgcn_mfma_f32_16x16x32_f16(ah[f * 2 + 1], bh[j * 2 + 1], a, 0, 0, 0);
                    acc[ih * 4 + f][j] = a;
                }
        }
        __syncthreads();
    }

    __syncthreads();
    float* stg = reinterpret_cast<float*>(smem) + w * 2048;
    const int colg0 = colBase + wc * 64;
#pragma unroll
    for (int rnd = 0; rnd < 4; ++rnd) {
        const int rowg0 = rowBase + wr * 128 + rnd * 32;
#pragma unroll
        for (int ii = 0; ii < 2; ++ii)
#pragma unroll
            for (int j = 0; j < 4; ++j)
#pragma unroll
                for (int r2 = 0; r2 < 4; ++r2)
                    stg[(ii * 16 + lg * 4 + r2) * 64 + j * 16 + lr] = acc[rnd * 2 + ii][j][r2];

        if constexpr (OMODE == 0) {
#pragma unroll
            for (int t = 0; t < 8; ++t) {
                const int idx = t * 256 + lane * 4;
                const int r = idx >> 6, c = idx & 63;
                const float4 v = *reinterpret_cast<const float4*>(&stg[idx]);
                *reinterpret_cast<float4*>(
                    &Cf[(long long)b * strideC + (long long)(rowg0 + r) * ldc + colg0 + c]) = v;
            }
        } else {  // OMODE == 3: V^T store  Ch[b2][col][s]
            const int b2 = rowg0 >> 11;
            const int s0 = rowg0 & 2047;
            const int colg = colg0 + lane;
            alignas(16) unsigned short u[32];
#pragma unroll
            for (int rr = 0; rr < 32; ++rr) u[rr] = f16_of(stg[rr * 64 + lane]);
            unsigned short* vp = Ch + (long long)b2 * (1024LL * 2048)
                               + (long long)colg * 2048 + s0;
#pragma unroll
            for (int q = 0; q < 4; ++q)
                *reinterpret_cast<uint4*>(vp + q * 8) =
                    *reinterpret_cast<const uint4*>(&u[q * 8]);
        }
        __syncthreads();
    }
}

// ---------------- helpers ----------------
__global__ __launch_bounds__(256) void split2_kernel(
    const float* __restrict__ in, unsigned short* __restrict__ hi,
    unsigned short* __restrict__ lo, long long n)
{
    for (long long i = ((long long)blockIdx.x * 256 + threadIdx.x) * 4; i < n;
         i += (long long)gridDim.x * 256 * 4) {
        float4 v = *reinterpret_cast<const float4*>(&in[i]);
        ushort4 h, l;
        h.x = f16_of(v.x); l.x = f16_of(v.x - f32_of(h.x));
        h.y = f16_of(v.y); l.y = f16_of(v.y - f32_of(h.y));
        h.z = f16_of(v.z); l.z = f16_of(v.z - f32_of(h.z));
        h.w = f16_of(v.w); l.w = f16_of(v.w - f32_of(h.w));
        *reinterpret_cast<ushort4*>(&hi[i]) = h;
        *reinterpret_cast<ushort4*>(&lo[i]) = l;
    }
}

__global__ __launch_bounds__(256) void tsplit_kernel(
    const float* __restrict__ in, unsigned short* __restrict__ hi,
    unsigned short* __restrict__ lo, int N)
{
    __shared__ float tile[64][65];
    const int bi = blockIdx.x * 64;
    const int bj = blockIdx.y * 64;
    const int t = threadIdx.x;
    const int c4 = (t & 15) * 4;
    const int r0 = (t >> 4) * 4;
#pragma unroll
    for (int rr = 0; rr < 4; ++rr) {
        float4 v = *reinterpret_cast<const float4*>(
            &in[(long long)(bi + r0 + rr) * N + bj + c4]);
        tile[r0 + rr][c4 + 0] = v.x;
        tile[r0 + rr][c4 + 1] = v.y;
        tile[r0 + rr][c4 + 2] = v.z;
        tile[r0 + rr][c4 + 3] = v.w;
    }
    __syncthreads();
    const int oc  = t >> 2;
    const int or0 = (t & 3) * 16;
    alignas(16) unsigned short uh[16], ul[16];
#pragma unroll
    for (int e = 0; e < 16; ++e) {
        const float f = tile[or0 + e][oc];
        const unsigned short h = f16_of(f);
        uh[e] = h;
        ul[e] = f16_of(f - f32_of(h));
    }
    unsigned short* hp = hi + (long long)(bj + oc) * N + bi + or0;
    unsigned short* lp = lo + (long long)(bj + oc) * N + bi + or0;
    *reinterpret_cast<uint4*>(hp)     = *reinterpret_cast<const uint4*>(&uh[0]);
    *reinterpret_cast<uint4*>(hp + 8) = *reinterpret_cast<const uint4*>(&uh[8]);
    *reinterpret_cast<uint4*>(lp)     = *reinterpret_cast<const uint4*>(&ul[0]);
    *reinterpret_cast<uint4*>(lp + 8) = *reinterpret_cast<const uint4*>(&ul[8]);
}

__global__ __launch_bounds__(256) void cvt_kernel(
    const float* __restrict__ in, unsigned short* __restrict__ out, long long n)
{
    for (long long i = ((long long)blockIdx.x * 256 + threadIdx.x) * 4; i < n;
         i += (long long)gridDim.x * 256 * 4) {
        float4 v = *reinterpret_cast<const float4*>(&in[i]);
        ushort4 h;
        h.x = f16_of(v.x); h.y = f16_of(v.y); h.z = f16_of(v.z); h.w = f16_of(v.w);
        *reinterpret_cast<ushort4*>(&out[i]) = h;
    }
}

__global__ __launch_bounds__(256) void softmax_kernel(
    float* __restrict__ s, unsigned short* __restrict__ p)
{
    const long long row = blockIdx.x;
    float* sp = s + row * 2048;
    const int tid = threadIdx.x;

    float v[8];
    *reinterpret_cast<float4*>(&v[0]) = *reinterpret_cast<const float4*>(&sp[tid * 8]);
    *reinterpret_cast<float4*>(&v[4]) = *reinterpret_cast<const float4*>(&sp[tid * 8 + 4]);

    float m = v[0];
#pragma unroll
    for (int i = 1; i < 8; ++i) m = fmaxf(m, v[i]);
#pragma unroll
    for (int off = 1; off < 64; off <<= 1) m = fmaxf(m, __shfl_xor(m, off));

    __shared__ float redm[4];
    __shared__ float reds[4];
    if ((tid & 63) == 0) redm[tid >> 6] = m;
    __syncthreads();
    m = fmaxf(fmaxf(redm[0], redm[1]), fmaxf(redm[2], redm[3]));

    float sum = 0.f;
#pragma unroll
    for (int i = 0; i < 8; ++i) {
        v[i] = __expf(v[i] - m);
        sum += v[i];
    }
#pragma unroll
    for (int off = 1; off < 64; off <<= 1) sum += __shfl_xor(sum, off);
    if ((tid & 63) == 0) reds[tid >> 6] = sum;
    __syncthreads();
    sum = reds[0] + reds[1] + reds[2] + reds[3];

    const float inv = 1.0f / sum;
#pragma unroll
    for (int i = 0; i < 8; ++i) v[i] *= inv;

    *reinterpret_cast<float4*>(&sp[tid * 8])     = *reinterpret_cast<const float4*>(&v[0]);
    *reinterpret_cast<float4*>(&sp[tid * 8 + 4]) = *reinterpret_cast<const float4*>(&v[4]);

    ushort4 o0, o1;
    o0.x = f16_of(v[0]); o0.y = f16_of(v[1]); o0.z = f16_of(v[2]); o0.w = f16_of(v[3]);
    o1.x = f16_of(v[4]); o1.y = f16_of(v[5]); o1.z = f16_of(v[6]); o1.w = f16_of(v[7]);
    *reinterpret_cast<ushort4*>(&p[row * 2048 + tid * 8])     = o0;
    *reinterpret_cast<ushort4*>(&p[row * 2048 + tid * 8 + 4]) = o1;
}

extern "C" void kernel_launch(void* const* d_in, const int* in_sizes, int n_in,
                              void* d_out, int out_size, void* d_ws, size_t ws_size,
                              hipStream_t stream)
{
    (void)in_sizes; (void)n_in; (void)out_size; (void)ws_size;

    const int S = 2048, D = 1024;
    const long long BS  = 8LL * S;          // 16384
    const long long SD  = (long long)S * D;
    const long long SS  = (long long)S * S;
    const long long BSD = BS * D;
    const long long DD  = (long long)D * D;

    const float* x    = (const float*)d_in[0];
    const int*   mask = (const int*)d_in[1];
    const float* wq   = (const float*)d_in[2];
    const float* wk   = (const float*)d_in[3];
    const float* wv   = (const float*)d_in[4];

    float* out = (float*)d_out;             // [BS, D] f32 (final)
    float* s   = out + BSD;                 // [B, S, S] f32 (final)

    // ws layout (halves):
    //   Gh [16384][1024] | Gl [16384][1024]   (later overwritten by p [B][S][S])
    //   Vt [B][D][S] | wvh | Mth
    unsigned short* Gh  = (unsigned short*)d_ws;
    unsigned short* Gl  = Gh + BSD;
    unsigned short* p   = Gh;               // 2*BSD halves, overwrites Gh+Gl
    unsigned short* Vt  = Gh + 2 * BSD;
    unsigned short* wvh = Gh + 3 * BSD;
    unsigned short* Mth = wvh + DD;

    // x split lives in d_out's out-region until PV overwrites it
    unsigned short* xh = (unsigned short*)out;
    unsigned short* xl = xh + BSD;
    // transposed weight splits live in d_out's s-region until scores overwrites it
    unsigned short* wqTh = (unsigned short*)s;   // [1024][1024] = wq^T hi
    unsigned short* wqTl = wqTh + DD;
    unsigned short* wkTh = wqTl + DD;
    unsigned short* wkTl = wkTh + DD;

    dim3 blk256(256), blk512(512);

    split2_kernel<<<dim3(2048), blk256, 0, stream>>>(x, xh, xl, BSD);
    tsplit_kernel<<<dim3(16, 16), blk256, 0, stream>>>(wq, wqTh, wqTl, D);
    tsplit_kernel<<<dim3(16, 16), blk256, 0, stream>>>(wk, wkTh, wkTl, D);

    // Mt[j][i] = sum_e wk[e][j]*wq[e][i]; A = (wkTh,wkTl) split, B = wqTh, plain f16 out
    gemm2<2><<<dim3(8, 4, 1), blk512, 0, stream>>>(
        wkTh, wkTl, 0, D, wqTh, 0, D,
        nullptr, Mth, nullptr, 0, D, D, nullptr, 0);

    // G = x @ Mt^T: A = (xh,xl) split, B = Mth; split-f16 out (Gh,Gl)
    gemm2<1><<<dim3(128, 4, 1), blk512, 0, stream>>>(
        xh, xl, 0, D, Mth, 0, D,
        nullptr, Gh, Gl, 0, D, D, nullptr, 0);

    // scores = G @ x^T + NEG_INF*mask: A = (Gh,Gl) split, B = xh; f32 out
    gemm2<0><<<dim3(16, 8, 8), blk512, 0, stream>>>(
        Gh, Gl, SD, D, xh, SD, D,
        s, nullptr, nullptr, SS, S, D, mask, S);

    // softmax in place + f16 p for PV (p overwrites Gh/Gl)
    softmax_kernel<<<dim3(16384), blk256, 0, stream>>>(s, p);

    // wv -> f16, then V^T = (x @ wv^T)^T directly (1-term, transposed store)
    cvt_kernel<<<dim3(512), blk256, 0, stream>>>(wv, wvh, DD);
    mfma_gemm1<3><<<dim3(64, 4, 1), blk512, 0, stream>>>(
        xh, 0, D, wvh, 0, D, nullptr, Vt, 0, D, D);

    // out = p @ V = p @ (V^T)^T  (1-term BK=64, NT form, f32 out)
    mfma_gemm1<0><<<dim3(8, 4, 8), blk512, 0, stream>>>(
        p, SS, S, Vt, SD, S, out, nullptr, SD, D, S);
}

// Round 14
// 379.059 us; speedup vs baseline: 1.1343x; 1.0719x over previous
//
#include <hip/hip_runtime.h>

#define NEG_INF_F (-1.0e9f)

typedef _Float16 f16x8 __attribute__((ext_vector_type(8)));
typedef float f32x4 __attribute__((ext_vector_type(4)));

__device__ inline unsigned short f16_of(float f) {
    _Float16 h = (_Float16)f;
    return __builtin_bit_cast(unsigned short, h);
}
__device__ inline float f32_of(unsigned short u) {
    return (float)__builtin_bit_cast(_Float16, u);
}

// async global->LDS, 16B per lane; LDS dest = wave-uniform base + lane*16
__device__ inline void gload16(const unsigned short* g, unsigned short* l) {
    __builtin_amdgcn_global_load_lds(
        (const __attribute__((address_space(1))) unsigned int*)g,
        (__attribute__((address_space(3))) unsigned int*)l, 16, 0, 0);
}

// [R][32]-f16 tile, chunk swizzle ^((r>>1)&3)
__device__ inline f16x8 frag32(const unsigned short* t, int r, int ch) {
    return *reinterpret_cast<const f16x8*>(&t[r * 32 + (ch ^ ((r >> 1) & 3)) * 8]);
}
// [R][64]-f16 tile, chunk swizzle ^(r&7)
__device__ inline f16x8 frag64(const unsigned short* t, int r, int ch) {
    return *reinterpret_cast<const f16x8*>(&t[r * 64 + (ch ^ (r & 7)) * 8]);
}

// Stage a 256x32 f16 tile: 2 gloads per wave.
__device__ inline void stage_256x32(const unsigned short* __restrict__ g0, int ldg, int k0,
                                    unsigned short* qbuf, int w, int lane) {
#pragma unroll
    for (int c = 0; c < 2; ++c) {
        const int r = c * 128 + w * 16 + (lane >> 2);
        const int co = ((lane & 3) ^ ((r >> 1) & 3)) * 8;
        gload16(g0 + (long long)r * ldg + k0 + co, qbuf + (c * 128 + w * 16) * 32);
    }
}
// Stage a 128x32 f16 tile: 1 gload per wave.
__device__ inline void stage_128x32(const unsigned short* __restrict__ g0, int ldg, int k0,
                                    unsigned short* qbuf, int w, int lane) {
    const int r = w * 16 + (lane >> 2);
    const int co = ((lane & 3) ^ ((r >> 1) & 3)) * 8;
    gload16(g0 + (long long)r * ldg + k0 + co, qbuf + (w * 16) * 32);
}

// ======== TERMS-2 GEMM (Mt, G): C = (Ah+Al) * B^T.  128x256, BK=32, 64KB ====
// 2 blocks/CU.  8 waves: 2 row-groups(64) x 4 col-groups(64), acc[4][4].
// XCD-aware block swizzle (grid size % 8 == 0).
// OMODE: 2 = plain f16 (Ch).
template <int OMODE>
__global__ __launch_bounds__(512, 2) void gemm2(
    const unsigned short* __restrict__ Ah_g, const unsigned short* __restrict__ Al_g,
    long long strideA, int lda,
    const unsigned short* __restrict__ Bh_g, long long strideB, int ldb,
    unsigned short* __restrict__ Ch, long long strideC, int ldc, int K)
{
    constexpr int BUF = 16384;  // ushorts = 32KB per buffer
    const int gx = gridDim.x, gy = gridDim.y;
    int bid = blockIdx.x + gx * (blockIdx.y + gy * blockIdx.z);
    const int nwg = gx * gy * gridDim.z;
    bid = (bid & 7) * (nwg >> 3) + (bid >> 3);
    const int bx = bid % gx;
    const int by = (bid / gx) % gy;
    const int b  = bid / (gx * gy);

    const int tid = threadIdx.x;
    const int w = tid >> 6, lane = tid & 63;
    const int wr = w & 1, wc = w >> 1;
    const int lr = lane & 15, lg = lane >> 4;
    const int rowBase = bx * 128;
    const int colBase = by * 256;

    __shared__ unsigned short smem[32768];  // 64 KB

    const unsigned short* Ah0 = Ah_g + (long long)b * strideA + (long long)rowBase * lda;
    const unsigned short* Al0 = Al_g + (long long)b * strideA + (long long)rowBase * lda;
    const unsigned short* Bh0 = Bh_g + (long long)b * strideB + (long long)colBase * ldb;

    f32x4 acc[4][4] = {};
    const int NT = K / 32;

    stage_128x32(Ah0, lda, 0, smem, w, lane);
    stage_128x32(Al0, lda, 0, smem + 4096, w, lane);
    stage_256x32(Bh0, ldb, 0, smem + 8192, w, lane);
    __syncthreads();

    for (int kt = 0; kt < NT; ++kt) {
        const unsigned short* cbuf = smem + (kt & 1) * BUF;
        if (kt + 1 < NT) {
            unsigned short* nbuf = smem + ((kt + 1) & 1) * BUF;
            const int k1 = (kt + 1) * 32;
            stage_128x32(Ah0, lda, k1, nbuf, w, lane);
            stage_128x32(Al0, lda, k1, nbuf + 4096, w, lane);
            stage_256x32(Bh0, ldb, k1, nbuf + 8192, w, lane);
        }
        const unsigned short* tAh = cbuf;
        const unsigned short* tAl = cbuf + 4096;
        const unsigned short* tB  = cbuf + 8192;
        f16x8 ah[4], al[4], bh[4];
#pragma unroll
        for (int i = 0; i < 4; ++i) {
            const int r = wr * 64 + i * 16 + lr;
            ah[i] = frag32(tAh, r, lg);
            al[i] = frag32(tAl, r, lg);
        }
#pragma unroll
        for (int j = 0; j < 4; ++j)
            bh[j] = frag32(tB, wc * 64 + j * 16 + lr, lg);
#pragma unroll
        for (int i = 0; i < 4; ++i)
#pragma unroll
            for (int j = 0; j < 4; ++j) {
                f32x4 a = acc[i][j];
                a = __builtin_amdgcn_mfma_f32_16x16x32_f16(ah[i], bh[j], a, 0, 0, 0);
                a = __builtin_amdgcn_mfma_f32_16x16x32_f16(al[i], bh[j], a, 0, 0, 0);
                acc[i][j] = a;
            }
        __syncthreads();
    }

    // ---- epilogue: per-wave private LDS bounce (8KB each) ----
    __syncthreads();
    float* stg = reinterpret_cast<float*>(smem) + w * 2048;
    const int colg0 = colBase + wc * 64;
#pragma unroll
    for (int rnd = 0; rnd < 2; ++rnd) {
        const int rowg0 = rowBase + wr * 64 + rnd * 32;
#pragma unroll
        for (int ii = 0; ii < 2; ++ii)
#pragma unroll
            for (int j = 0; j < 4; ++j)
#pragma unroll
                for (int r2 = 0; r2 < 4; ++r2)
                    stg[(ii * 16 + lg * 4 + r2) * 64 + j * 16 + lr] = acc[rnd * 2 + ii][j][r2];

#pragma unroll
        for (int t = 0; t < 8; ++t) {
            const int idx = t * 256 + lane * 4;
            const int r = idx >> 6, c = idx & 63;
            const float4 v = *reinterpret_cast<const float4*>(&stg[idx]);
            ushort4 h;
            h.x = f16_of(v.x); h.y = f16_of(v.y);
            h.z = f16_of(v.z); h.w = f16_of(v.w);
            *reinterpret_cast<ushort4*>(
                &Ch[(long long)b * strideC + (long long)(rowg0 + r) * ldc + colg0 + c]) = h;
        }
    }
}

// ======== TERMS-1 GEMM (scores, Vproj, PV): 256x256, BK=64, 2-barrier =======
__device__ inline void stage_ktile1(
    const unsigned short* __restrict__ Ah0, int lda,
    const unsigned short* __restrict__ Bh0, int ldb,
    int k0, unsigned short* buf, int w, int lane)
{
#pragma unroll
    for (int c = 0; c < 4; ++c) {
        const int r = c * 64 + w * 8 + (lane >> 3);
        const int co = ((lane & 7) ^ (r & 7)) * 8;
        const int lb = (c * 64 + w * 8) * 64;
        gload16(Ah0 + (long long)r * lda + k0 + co, buf + lb);
        gload16(Bh0 + (long long)r * ldb + k0 + co, buf + 16384 + lb);
    }
}

// OMODE: 0 = f32 C (+ optional NEG_INF*mask[col]); 3 = f16 V^T store Ch[b2][col][s].
template <int OMODE>
__global__ __launch_bounds__(512, 2) void mfma_gemm1(
    const unsigned short* __restrict__ Ah_g, long long strideA, int lda,
    const unsigned short* __restrict__ Bh_g, long long strideB, int ldb,
    float* __restrict__ Cf, unsigned short* __restrict__ Ch,
    long long strideC, int ldc, int K,
    const int* __restrict__ mask, long long strideMask)
{
    const int b = blockIdx.z;
    const int tid = threadIdx.x;
    const int w = tid >> 6, lane = tid & 63;
    const int wr = w >> 2, wc = w & 3;
    const int lr = lane & 15, lg = lane >> 4;
    const int rowBase = blockIdx.x * 256;
    const int colBase = blockIdx.y * 256;

    __shared__ unsigned short smem[65536];  // 128 KB: 2 x 64KB

    const unsigned short* Ah0 = Ah_g + (long long)b * strideA + (long long)rowBase * lda;
    const unsigned short* Bh0 = Bh_g + (long long)b * strideB + (long long)colBase * ldb;

    f32x4 acc[8][4] = {};
    const int NT = K / 64;

    stage_ktile1(Ah0, lda, Bh0, ldb, 0, smem, w, lane);
    __syncthreads();

    for (int kt = 0; kt < NT; ++kt) {
        const unsigned short* cbuf = smem + (kt & 1) * 32768;
        if (kt + 1 < NT)
            stage_ktile1(Ah0, lda, Bh0, ldb, (kt + 1) * 64,
                         smem + ((kt + 1) & 1) * 32768, w, lane);

        const unsigned short* tA = cbuf;
        const unsigned short* tB = cbuf + 16384;
        f16x8 bh[8];
#pragma unroll
        for (int j = 0; j < 4; ++j)
#pragma unroll
            for (int ks = 0; ks < 2; ++ks)
                bh[j * 2 + ks] = frag64(tB, wc * 64 + j * 16 + lr, ks * 4 + lg);
#pragma unroll
        for (int ih = 0; ih < 2; ++ih) {
            f16x8 ah[8];
#pragma unroll
            for (int f = 0; f < 4; ++f)
#pragma unroll
                for (int ks = 0; ks < 2; ++ks)
                    ah[f * 2 + ks] = frag64(tA, wr * 128 + ih * 64 + f * 16 + lr, ks * 4 + lg);
#pragma unroll
            for (int f = 0; f < 4; ++f)
#pragma unroll
                for (int j = 0; j < 4; ++j) {
                    f32x4 a = acc[ih * 4 + f][j];
                    a = __builtin_amdgcn_mfma_f32_16x16x32_f16(ah[f * 2 + 0], bh[j * 2 + 0], a, 0, 0, 0);
                    a = __builtin_amdgcn_mfma_f32_16x16x32_f16(ah[f * 2 + 1], bh[j * 2 + 1], a, 0, 0, 0);
                    acc[ih * 4 + f][j] = a;
                }
        }
        __syncthreads();
    }

    __syncthreads();
    float* stg = reinterpret_cast<float*>(smem) + w * 2048;
    const int colg0 = colBase + wc * 64;
#pragma unroll
    for (int rnd = 0; rnd < 4; ++rnd) {
        const int rowg0 = rowBase + wr * 128 + rnd * 32;
#pragma unroll
        for (int ii = 0; ii < 2; ++ii)
#pragma unroll
            for (int j = 0; j < 4; ++j)
#pragma unroll
                for (int r2 = 0; r2 < 4; ++r2)
                    stg[(ii * 16 + lg * 4 + r2) * 64 + j * 16 + lr] = acc[rnd * 2 + ii][j][r2];

        if constexpr (OMODE == 0) {
#pragma unroll
            for (int t = 0; t < 8; ++t) {
                const int idx = t * 256 + lane * 4;
                const int r = idx >> 6, c = idx & 63;
                float4 v = *reinterpret_cast<const float4*>(&stg[idx]);
                const int colg = colg0 + c;
                if (mask != nullptr) {
                    const int4 mv = *reinterpret_cast<const int4*>(
                        &mask[(long long)b * strideMask + colg]);
                    v.x += NEG_INF_F * (float)mv.x;
                    v.y += NEG_INF_F * (float)mv.y;
                    v.z += NEG_INF_F * (float)mv.z;
                    v.w += NEG_INF_F * (float)mv.w;
                }
                *reinterpret_cast<float4*>(
                    &Cf[(long long)b * strideC + (long long)(rowg0 + r) * ldc + colg]) = v;
            }
        } else {  // OMODE == 3: V^T store  Ch[b2][col][s]
            const int b2 = rowg0 >> 11;
            const int s0 = rowg0 & 2047;
            const int colg = colg0 + lane;
            alignas(16) unsigned short u[32];
#pragma unroll
            for (int rr = 0; rr < 32; ++rr) u[rr] = f16_of(stg[rr * 64 + lane]);
            unsigned short* vp = Ch + (long long)b2 * (1024LL * 2048)
                               + (long long)colg * 2048 + s0;
#pragma unroll
            for (int q = 0; q < 4; ++q)
                *reinterpret_cast<uint4*>(vp + q * 8) =
                    *reinterpret_cast<const uint4*>(&u[q * 8]);
        }
        __syncthreads();
    }
}

// ---------------- helpers ----------------
__global__ __launch_bounds__(256) void split2_kernel(
    const float* __restrict__ in, unsigned short* __restrict__ hi,
    unsigned short* __restrict__ lo, long long n)
{
    for (long long i = ((long long)blockIdx.x * 256 + threadIdx.x) * 4; i < n;
         i += (long long)gridDim.x * 256 * 4) {
        float4 v = *reinterpret_cast<const float4*>(&in[i]);
        ushort4 h, l;
        h.x = f16_of(v.x); l.x = f16_of(v.x - f32_of(h.x));
        h.y = f16_of(v.y); l.y = f16_of(v.y - f32_of(h.y));
        h.z = f16_of(v.z); l.z = f16_of(v.z - f32_of(h.z));
        h.w = f16_of(v.w); l.w = f16_of(v.w - f32_of(h.w));
        *reinterpret_cast<ushort4*>(&hi[i]) = h;
        *reinterpret_cast<ushort4*>(&lo[i]) = l;
    }
}

__global__ __launch_bounds__(256) void tsplit_kernel(
    const float* __restrict__ in, unsigned short* __restrict__ hi,
    unsigned short* __restrict__ lo, int N)
{
    __shared__ float tile[64][65];
    const int bi = blockIdx.x * 64;
    const int bj = blockIdx.y * 64;
    const int t = threadIdx.x;
    const int c4 = (t & 15) * 4;
    const int r0 = (t >> 4) * 4;
#pragma unroll
    for (int rr = 0; rr < 4; ++rr) {
        float4 v = *reinterpret_cast<const float4*>(
            &in[(long long)(bi + r0 + rr) * N + bj + c4]);
        tile[r0 + rr][c4 + 0] = v.x;
        tile[r0 + rr][c4 + 1] = v.y;
        tile[r0 + rr][c4 + 2] = v.z;
        tile[r0 + rr][c4 + 3] = v.w;
    }
    __syncthreads();
    const int oc  = t >> 2;
    const int or0 = (t & 3) * 16;
    alignas(16) unsigned short uh[16], ul[16];
#pragma unroll
    for (int e = 0; e < 16; ++e) {
        const float f = tile[or0 + e][oc];
        const unsigned short h = f16_of(f);
        uh[e] = h;
        ul[e] = f16_of(f - f32_of(h));
    }
    unsigned short* hp = hi + (long long)(bj + oc) * N + bi + or0;
    unsigned short* lp = lo + (long long)(bj + oc) * N + bi + or0;
    *reinterpret_cast<uint4*>(hp)     = *reinterpret_cast<const uint4*>(&uh[0]);
    *reinterpret_cast<uint4*>(hp + 8) = *reinterpret_cast<const uint4*>(&uh[8]);
    *reinterpret_cast<uint4*>(lp)     = *reinterpret_cast<const uint4*>(&ul[0]);
    *reinterpret_cast<uint4*>(lp + 8) = *reinterpret_cast<const uint4*>(&ul[8]);
}

__global__ __launch_bounds__(256) void cvt_kernel(
    const float* __restrict__ in, unsigned short* __restrict__ out, long long n)
{
    for (long long i = ((long long)blockIdx.x * 256 + threadIdx.x) * 4; i < n;
         i += (long long)gridDim.x * 256 * 4) {
        float4 v = *reinterpret_cast<const float4*>(&in[i]);
        ushort4 h;
        h.x = f16_of(v.x); h.y = f16_of(v.y); h.z = f16_of(v.z); h.w = f16_of(v.w);
        *reinterpret_cast<ushort4*>(&out[i]) = h;
    }
}

__global__ __launch_bounds__(256) void softmax_kernel(
    float* __restrict__ s, unsigned short* __restrict__ p)
{
    const long long row = blockIdx.x;
    float* sp = s + row * 2048;
    const int tid = threadIdx.x;

    float v[8];
    *reinterpret_cast<float4*>(&v[0]) = *reinterpret_cast<const float4*>(&sp[tid * 8]);
    *reinterpret_cast<float4*>(&v[4]) = *reinterpret_cast<const float4*>(&sp[tid * 8 + 4]);

    float m = v[0];
#pragma unroll
    for (int i = 1; i < 8; ++i) m = fmaxf(m, v[i]);
#pragma unroll
    for (int off = 1; off < 64; off <<= 1) m = fmaxf(m, __shfl_xor(m, off));

    __shared__ float redm[4];
    __shared__ float reds[4];
    if ((tid & 63) == 0) redm[tid >> 6] = m;
    __syncthreads();
    m = fmaxf(fmaxf(redm[0], redm[1]), fmaxf(redm[2], redm[3]));

    float sum = 0.f;
#pragma unroll
    for (int i = 0; i < 8; ++i) {
        v[i] = __expf(v[i] - m);
        sum += v[i];
    }
#pragma unroll
    for (int off = 1; off < 64; off <<= 1) sum += __shfl_xor(sum, off);
    if ((tid & 63) == 0) reds[tid >> 6] = sum;
    __syncthreads();
    sum = reds[0] + reds[1] + reds[2] + reds[3];

    const float inv = 1.0f / sum;
#pragma unroll
    for (int i = 0; i < 8; ++i) v[i] *= inv;

    *reinterpret_cast<float4*>(&sp[tid * 8])     = *reinterpret_cast<const float4*>(&v[0]);
    *reinterpret_cast<float4*>(&sp[tid * 8 + 4]) = *reinterpret_cast<const float4*>(&v[4]);

    ushort4 o0, o1;
    o0.x = f16_of(v[0]); o0.y = f16_of(v[1]); o0.z = f16_of(v[2]); o0.w = f16_of(v[3]);
    o1.x = f16_of(v[4]); o1.y = f16_of(v[5]); o1.z = f16_of(v[6]); o1.w = f16_of(v[7]);
    *reinterpret_cast<ushort4*>(&p[row * 2048 + tid * 8])     = o0;
    *reinterpret_cast<ushort4*>(&p[row * 2048 + tid * 8 + 4]) = o1;
}

extern "C" void kernel_launch(void* const* d_in, const int* in_sizes, int n_in,
                              void* d_out, int out_size, void* d_ws, size_t ws_size,
                              hipStream_t stream)
{
    (void)in_sizes; (void)n_in; (void)out_size; (void)ws_size;

    const int S = 2048, D = 1024;
    const long long BS  = 8LL * S;          // 16384
    const long long SD  = (long long)S * D;
    const long long SS  = (long long)S * S;
    const long long BSD = BS * D;
    const long long DD  = (long long)D * D;

    const float* x    = (const float*)d_in[0];
    const int*   mask = (const int*)d_in[1];
    const float* wq   = (const float*)d_in[2];
    const float* wk   = (const float*)d_in[3];
    const float* wv   = (const float*)d_in[4];

    float* out = (float*)d_out;             // [BS, D] f32 (final)
    float* s   = out + BSD;                 // [B, S, S] f32 (final)

    // ws layout (halves):
    //   G [16384][1024] | (free BSD)        <- later p [B][S][S] = 2*BSD halves
    //   Vt [B][D][S] | wvh | Mth
    unsigned short* G   = (unsigned short*)d_ws;
    unsigned short* p   = G;                // 2*BSD halves, overwrites G + free
    unsigned short* Vt  = G + 2 * BSD;
    unsigned short* wvh = G + 3 * BSD;
    unsigned short* Mth = wvh + DD;

    // x split lives in d_out's out-region until PV overwrites it
    unsigned short* xh = (unsigned short*)out;
    unsigned short* xl = xh + BSD;
    // transposed weight splits live in d_out's s-region until scores overwrites it
    unsigned short* wqTh = (unsigned short*)s;   // [1024][1024] = wq^T hi
    unsigned short* wqTl = wqTh + DD;
    unsigned short* wkTh = wqTl + DD;
    unsigned short* wkTl = wkTh + DD;

    dim3 blk256(256), blk512(512);

    split2_kernel<<<dim3(2048), blk256, 0, stream>>>(x, xh, xl, BSD);
    tsplit_kernel<<<dim3(16, 16), blk256, 0, stream>>>(wq, wqTh, wqTl, D);
    tsplit_kernel<<<dim3(16, 16), blk256, 0, stream>>>(wk, wkTh, wkTl, D);

    // Mt[j][i] = sum_e wk[e][j]*wq[e][i]; A = (wkTh,wkTl) split, B = wqTh, f16 out
    gemm2<2><<<dim3(8, 4, 1), blk512, 0, stream>>>(
        wkTh, wkTl, 0, D, wqTh, 0, D, Mth, 0, D, D);

    // G = x @ Mt^T: A = (xh,xl) split, B = Mth; plain f16 out (hi only)
    gemm2<2><<<dim3(128, 4, 1), blk512, 0, stream>>>(
        xh, xl, 0, D, Mth, 0, D, G, 0, D, D);

    // scores = G @ x^T + NEG_INF*mask  (1-term, 256x256 BK=64 kernel, f32 out)
    mfma_gemm1<0><<<dim3(8, 8, 8), blk512, 0, stream>>>(
        G, SD, D, xh, SD, D,
        s, nullptr, SS, S, D, mask, S);

    // softmax in place + f16 p for PV (p overwrites G)
    softmax_kernel<<<dim3(16384), blk256, 0, stream>>>(s, p);

    // wv -> f16, then V^T = (x @ wv^T)^T directly (transposed store)
    cvt_kernel<<<dim3(512), blk256, 0, stream>>>(wv, wvh, DD);
    mfma_gemm1<3><<<dim3(64, 4, 1), blk512, 0, stream>>>(
        xh, 0, D, wvh, 0, D, nullptr, Vt, 0, D, D, nullptr, 0);

    // out = p @ V = p @ (V^T)^T  (f32 out)
    mfma_gemm1<0><<<dim3(8, 4, 8), blk512, 0, stream>>>(
        p, SS, S, Vt, SD, S, out, nullptr, SD, D, S, nullptr, 0);
}

// Round 15
// 322.255 us; speedup vs baseline: 1.3343x; 1.1763x over previous
//
#include <hip/hip_runtime.h>

#define NEG_INF_F (-1.0e9f)

typedef _Float16 f16x8 __attribute__((ext_vector_type(8)));
typedef float f32x4 __attribute__((ext_vector_type(4)));

__device__ inline unsigned short f16_of(float f) {
    _Float16 h = (_Float16)f;
    return __builtin_bit_cast(unsigned short, h);
}
__device__ inline float f32_of(unsigned short u) {
    return (float)__builtin_bit_cast(_Float16, u);
}

// async global->LDS, 16B per lane; LDS dest = wave-uniform base + lane*16
__device__ inline void gload16(const unsigned short* g, unsigned short* l) {
    __builtin_amdgcn_global_load_lds(
        (const __attribute__((address_space(1))) unsigned int*)g,
        (__attribute__((address_space(3))) unsigned int*)l, 16, 0, 0);
}

// [R][32]-f16 tile, chunk swizzle ^((r>>1)&3)
__device__ inline f16x8 frag32(const unsigned short* t, int r, int ch) {
    return *reinterpret_cast<const f16x8*>(&t[r * 32 + (ch ^ ((r >> 1) & 3)) * 8]);
}
// [R][64]-f16 tile, chunk swizzle ^(r&7)
__device__ inline f16x8 frag64(const unsigned short* t, int r, int ch) {
    return *reinterpret_cast<const f16x8*>(&t[r * 64 + (ch ^ (r & 7)) * 8]);
}

// Stage a 256x32 f16 tile: 2 gloads per wave.
__device__ inline void stage_256x32(const unsigned short* __restrict__ g0, int ldg, int k0,
                                    unsigned short* qbuf, int w, int lane) {
#pragma unroll
    for (int c = 0; c < 2; ++c) {
        const int r = c * 128 + w * 16 + (lane >> 2);
        const int co = ((lane & 3) ^ ((r >> 1) & 3)) * 8;
        gload16(g0 + (long long)r * ldg + k0 + co, qbuf + (c * 128 + w * 16) * 32);
    }
}
// Stage a 128x32 f16 tile: 1 gload per wave.
__device__ inline void stage_128x32(const unsigned short* __restrict__ g0, int ldg, int k0,
                                    unsigned short* qbuf, int w, int lane) {
    const int r = w * 16 + (lane >> 2);
    const int co = ((lane & 3) ^ ((r >> 1) & 3)) * 8;
    gload16(g0 + (long long)r * ldg + k0 + co, qbuf + (w * 16) * 32);
}

// ======== TERMS-2 GEMM (Mt only): C = (Ah+Al) * B^T.  128x256, BK=32 ========
__global__ __launch_bounds__(512, 2) void gemm2(
    const unsigned short* __restrict__ Ah_g, const unsigned short* __restrict__ Al_g,
    int lda,
    const unsigned short* __restrict__ Bh_g, int ldb,
    unsigned short* __restrict__ Ch, int ldc, int K)
{
    constexpr int BUF = 16384;
    const int tid = threadIdx.x;
    const int w = tid >> 6, lane = tid & 63;
    const int wr = w & 1, wc = w >> 1;
    const int lr = lane & 15, lg = lane >> 4;
    const int rowBase = blockIdx.x * 128;
    const int colBase = blockIdx.y * 256;

    __shared__ unsigned short smem[32768];

    const unsigned short* Ah0 = Ah_g + (long long)rowBase * lda;
    const unsigned short* Al0 = Al_g + (long long)rowBase * lda;
    const unsigned short* Bh0 = Bh_g + (long long)colBase * ldb;

    f32x4 acc[4][4] = {};
    const int NT = K / 32;

    stage_128x32(Ah0, lda, 0, smem, w, lane);
    stage_128x32(Al0, lda, 0, smem + 4096, w, lane);
    stage_256x32(Bh0, ldb, 0, smem + 8192, w, lane);
    __syncthreads();

    for (int kt = 0; kt < NT; ++kt) {
        const unsigned short* cbuf = smem + (kt & 1) * BUF;
        if (kt + 1 < NT) {
            unsigned short* nbuf = smem + ((kt + 1) & 1) * BUF;
            const int k1 = (kt + 1) * 32;
            stage_128x32(Ah0, lda, k1, nbuf, w, lane);
            stage_128x32(Al0, lda, k1, nbuf + 4096, w, lane);
            stage_256x32(Bh0, ldb, k1, nbuf + 8192, w, lane);
        }
        const unsigned short* tAh = cbuf;
        const unsigned short* tAl = cbuf + 4096;
        const unsigned short* tB  = cbuf + 8192;
        f16x8 ah[4], al[4], bh[4];
#pragma unroll
        for (int i = 0; i < 4; ++i) {
            const int r = wr * 64 + i * 16 + lr;
            ah[i] = frag32(tAh, r, lg);
            al[i] = frag32(tAl, r, lg);
        }
#pragma unroll
        for (int j = 0; j < 4; ++j)
            bh[j] = frag32(tB, wc * 64 + j * 16 + lr, lg);
#pragma unroll
        for (int i = 0; i < 4; ++i)
#pragma unroll
            for (int j = 0; j < 4; ++j) {
                f32x4 a = acc[i][j];
                a = __builtin_amdgcn_mfma_f32_16x16x32_f16(ah[i], bh[j], a, 0, 0, 0);
                a = __builtin_amdgcn_mfma_f32_16x16x32_f16(al[i], bh[j], a, 0, 0, 0);
                acc[i][j] = a;
            }
        __syncthreads();
    }

    __syncthreads();
    float* stg = reinterpret_cast<float*>(smem) + w * 2048;
    const int colg0 = colBase + wc * 64;
#pragma unroll
    for (int rnd = 0; rnd < 2; ++rnd) {
        const int rowg0 = rowBase + wr * 64 + rnd * 32;
#pragma unroll
        for (int ii = 0; ii < 2; ++ii)
#pragma unroll
            for (int j = 0; j < 4; ++j)
#pragma unroll
                for (int r2 = 0; r2 < 4; ++r2)
                    stg[(ii * 16 + lg * 4 + r2) * 64 + j * 16 + lr] = acc[rnd * 2 + ii][j][r2];

#pragma unroll
        for (int t = 0; t < 8; ++t) {
            const int idx = t * 256 + lane * 4;
            const int r = idx >> 6, c = idx & 63;
            const float4 v = *reinterpret_cast<const float4*>(&stg[idx]);
            ushort4 h;
            h.x = f16_of(v.x); h.y = f16_of(v.y);
            h.z = f16_of(v.z); h.w = f16_of(v.w);
            *reinterpret_cast<ushort4*>(
                &Ch[(long long)(rowg0 + r) * ldc + colg0 + c]) = h;
        }
    }
}

// ======== TERMS-1 GEMM: 256x256, BK=64, 2-barrier loop ======================
__device__ inline void stage_ktile1(
    const unsigned short* __restrict__ Ah0, int lda,
    const unsigned short* __restrict__ Bh0, int ldb,
    int k0, unsigned short* buf, int w, int lane)
{
#pragma unroll
    for (int c = 0; c < 4; ++c) {
        const int r = c * 64 + w * 8 + (lane >> 3);
        const int co = ((lane & 7) ^ (r & 7)) * 8;
        const int lb = (c * 64 + w * 8) * 64;
        gload16(Ah0 + (long long)r * lda + k0 + co, buf + lb);
        gload16(Bh0 + (long long)r * ldb + k0 + co, buf + 16384 + lb);
    }
}

// OMODE: 0 = f32 C (+ optional NEG_INF*mask[col]);
//        4 = fused GV: cols<1024 -> plain f16 G (Ch, ldc); cols>=1024 -> f16
//            V^T store Ch2[b2][col-1024][s]  (rows are [B*S], b2=row>>11).
template <int OMODE>
__global__ __launch_bounds__(512, 2) void mfma_gemm1(
    const unsigned short* __restrict__ Ah_g, long long strideA, int lda,
    const unsigned short* __restrict__ Bh_g, long long strideB, int ldb,
    float* __restrict__ Cf, unsigned short* __restrict__ Ch, unsigned short* __restrict__ Ch2,
    long long strideC, int ldc, int K,
    const int* __restrict__ mask, long long strideMask)
{
    const int b = blockIdx.z;
    const int tid = threadIdx.x;
    const int w = tid >> 6, lane = tid & 63;
    const int wr = w >> 2, wc = w & 3;
    const int lr = lane & 15, lg = lane >> 4;
    const int rowBase = blockIdx.x * 256;
    const int colBase = blockIdx.y * 256;

    __shared__ unsigned short smem[65536];  // 128 KB: 2 x 64KB

    const unsigned short* Ah0 = Ah_g + (long long)b * strideA + (long long)rowBase * lda;
    const unsigned short* Bh0 = Bh_g + (long long)b * strideB + (long long)colBase * ldb;

    f32x4 acc[8][4] = {};
    const int NT = K / 64;

    stage_ktile1(Ah0, lda, Bh0, ldb, 0, smem, w, lane);
    __syncthreads();

    for (int kt = 0; kt < NT; ++kt) {
        const unsigned short* cbuf = smem + (kt & 1) * 32768;
        if (kt + 1 < NT)
            stage_ktile1(Ah0, lda, Bh0, ldb, (kt + 1) * 64,
                         smem + ((kt + 1) & 1) * 32768, w, lane);

        const unsigned short* tA = cbuf;
        const unsigned short* tB = cbuf + 16384;
        f16x8 bh[8];
#pragma unroll
        for (int j = 0; j < 4; ++j)
#pragma unroll
            for (int ks = 0; ks < 2; ++ks)
                bh[j * 2 + ks] = frag64(tB, wc * 64 + j * 16 + lr, ks * 4 + lg);
#pragma unroll
        for (int ih = 0; ih < 2; ++ih) {
            f16x8 ah[8];
#pragma unroll
            for (int f = 0; f < 4; ++f)
#pragma unroll
                for (int ks = 0; ks < 2; ++ks)
                    ah[f * 2 + ks] = frag64(tA, wr * 128 + ih * 64 + f * 16 + lr, ks * 4 + lg);
#pragma unroll
            for (int f = 0; f < 4; ++f)
#pragma unroll
                for (int j = 0; j < 4; ++j) {
                    f32x4 a = acc[ih * 4 + f][j];
                    a = __builtin_amdgcn_mfma_f32_16x16x32_f16(ah[f * 2 + 0], bh[j * 2 + 0], a, 0, 0, 0);
                    a = __builtin_amdgcn_mfma_f32_16x16x32_f16(ah[f * 2 + 1], bh[j * 2 + 1], a, 0, 0, 0);
                    acc[ih * 4 + f][j] = a;
                }
        }
        __syncthreads();
    }

    __syncthreads();
    float* stg = reinterpret_cast<float*>(smem) + w * 2048;
    const int colg0 = colBase + wc * 64;
#pragma unroll
    for (int rnd = 0; rnd < 4; ++rnd) {
        const int rowg0 = rowBase + wr * 128 + rnd * 32;
#pragma unroll
        for (int ii = 0; ii < 2; ++ii)
#pragma unroll
            for (int j = 0; j < 4; ++j)
#pragma unroll
                for (int r2 = 0; r2 < 4; ++r2)
                    stg[(ii * 16 + lg * 4 + r2) * 64 + j * 16 + lr] = acc[rnd * 2 + ii][j][r2];

        if constexpr (OMODE == 0) {
#pragma unroll
            for (int t = 0; t < 8; ++t) {
                const int idx = t * 256 + lane * 4;
                const int r = idx >> 6, c = idx & 63;
                float4 v = *reinterpret_cast<const float4*>(&stg[idx]);
                const int colg = colg0 + c;
                if (mask != nullptr) {
                    const int4 mv = *reinterpret_cast<const int4*>(
                        &mask[(long long)b * strideMask + colg]);
                    v.x += NEG_INF_F * (float)mv.x;
                    v.y += NEG_INF_F * (float)mv.y;
                    v.z += NEG_INF_F * (float)mv.z;
                    v.w += NEG_INF_F * (float)mv.w;
                }
                *reinterpret_cast<float4*>(
                    &Cf[(long long)b * strideC + (long long)(rowg0 + r) * ldc + colg]) = v;
            }
        } else {  // OMODE == 4: fused G | V^T
            if (colBase < 1024) {
#pragma unroll
                for (int t = 0; t < 8; ++t) {
                    const int idx = t * 256 + lane * 4;
                    const int r = idx >> 6, c = idx & 63;
                    const float4 v = *reinterpret_cast<const float4*>(&stg[idx]);
                    ushort4 h;
                    h.x = f16_of(v.x); h.y = f16_of(v.y);
                    h.z = f16_of(v.z); h.w = f16_of(v.w);
                    *reinterpret_cast<ushort4*>(
                        &Ch[(long long)(rowg0 + r) * ldc + colg0 + c]) = h;
                }
            } else {
                const int b2 = rowg0 >> 11;
                const int s0 = rowg0 & 2047;
                const int vcol = colg0 - 1024 + lane;
                alignas(16) unsigned short u[32];
#pragma unroll
                for (int rr = 0; rr < 32; ++rr) u[rr] = f16_of(stg[rr * 64 + lane]);
                unsigned short* vp = Ch2 + (long long)b2 * (1024LL * 2048)
                                   + (long long)vcol * 2048 + s0;
#pragma unroll
                for (int q = 0; q < 4; ++q)
                    *reinterpret_cast<uint4*>(vp + q * 8) =
                        *reinterpret_cast<const uint4*>(&u[q * 8]);
            }
        }
        __syncthreads();
    }
}

// ---------------- helpers ----------------
// f32 -> f16
__global__ __launch_bounds__(256) void cvt_kernel(
    const float* __restrict__ in, unsigned short* __restrict__ out, long long n)
{
    for (long long i = ((long long)blockIdx.x * 256 + threadIdx.x) * 4; i < n;
         i += (long long)gridDim.x * 256 * 4) {
        float4 v = *reinterpret_cast<const float4*>(&in[i]);
        ushort4 h;
        h.x = f16_of(v.x); h.y = f16_of(v.y); h.z = f16_of(v.z); h.w = f16_of(v.w);
        *reinterpret_cast<ushort4*>(&out[i]) = h;
    }
}

// f32 [N][N] -> TRANSPOSED hi/lo f16 (for Mt's split A side)
__global__ __launch_bounds__(256) void tsplit_kernel(
    const float* __restrict__ in, unsigned short* __restrict__ hi,
    unsigned short* __restrict__ lo, int N)
{
    __shared__ float tile[64][65];
    const int bi = blockIdx.x * 64;
    const int bj = blockIdx.y * 64;
    const int t = threadIdx.x;
    const int c4 = (t & 15) * 4;
    const int r0 = (t >> 4) * 4;
#pragma unroll
    for (int rr = 0; rr < 4; ++rr) {
        float4 v = *reinterpret_cast<const float4*>(
            &in[(long long)(bi + r0 + rr) * N + bj + c4]);
        tile[r0 + rr][c4 + 0] = v.x;
        tile[r0 + rr][c4 + 1] = v.y;
        tile[r0 + rr][c4 + 2] = v.z;
        tile[r0 + rr][c4 + 3] = v.w;
    }
    __syncthreads();
    const int oc  = t >> 2;
    const int or0 = (t & 3) * 16;
    alignas(16) unsigned short uh[16], ul[16];
#pragma unroll
    for (int e = 0; e < 16; ++e) {
        const float f = tile[or0 + e][oc];
        const unsigned short h = f16_of(f);
        uh[e] = h;
        ul[e] = f16_of(f - f32_of(h));
    }
    unsigned short* hp = hi + (long long)(bj + oc) * N + bi + or0;
    unsigned short* lp = lo + (long long)(bj + oc) * N + bi + or0;
    *reinterpret_cast<uint4*>(hp)     = *reinterpret_cast<const uint4*>(&uh[0]);
    *reinterpret_cast<uint4*>(hp + 8) = *reinterpret_cast<const uint4*>(&uh[8]);
    *reinterpret_cast<uint4*>(lp)     = *reinterpret_cast<const uint4*>(&ul[0]);
    *reinterpret_cast<uint4*>(lp + 8) = *reinterpret_cast<const uint4*>(&ul[8]);
}

// In-place f32 row softmax (rows=16384, cols=2048) + f16 copy for PV.
__global__ __launch_bounds__(256) void softmax_kernel(
    float* __restrict__ s, unsigned short* __restrict__ p)
{
    const long long row = blockIdx.x;
    float* sp = s + row * 2048;
    const int tid = threadIdx.x;

    float v[8];
    *reinterpret_cast<float4*>(&v[0]) = *reinterpret_cast<const float4*>(&sp[tid * 8]);
    *reinterpret_cast<float4*>(&v[4]) = *reinterpret_cast<const float4*>(&sp[tid * 8 + 4]);

    float m = v[0];
#pragma unroll
    for (int i = 1; i < 8; ++i) m = fmaxf(m, v[i]);
#pragma unroll
    for (int off = 1; off < 64; off <<= 1) m = fmaxf(m, __shfl_xor(m, off));

    __shared__ float redm[4];
    __shared__ float reds[4];
    if ((tid & 63) == 0) redm[tid >> 6] = m;
    __syncthreads();
    m = fmaxf(fmaxf(redm[0], redm[1]), fmaxf(redm[2], redm[3]));

    float sum = 0.f;
#pragma unroll
    for (int i = 0; i < 8; ++i) {
        v[i] = __expf(v[i] - m);
        sum += v[i];
    }
#pragma unroll
    for (int off = 1; off < 64; off <<= 1) sum += __shfl_xor(sum, off);
    if ((tid & 63) == 0) reds[tid >> 6] = sum;
    __syncthreads();
    sum = reds[0] + reds[1] + reds[2] + reds[3];

    const float inv = 1.0f / sum;
#pragma unroll
    for (int i = 0; i < 8; ++i) v[i] *= inv;

    *reinterpret_cast<float4*>(&sp[tid * 8])     = *reinterpret_cast<const float4*>(&v[0]);
    *reinterpret_cast<float4*>(&sp[tid * 8 + 4]) = *reinterpret_cast<const float4*>(&v[4]);

    ushort4 o0, o1;
    o0.x = f16_of(v[0]); o0.y = f16_of(v[1]); o0.z = f16_of(v[2]); o0.w = f16_of(v[3]);
    o1.x = f16_of(v[4]); o1.y = f16_of(v[5]); o1.z = f16_of(v[6]); o1.w = f16_of(v[7]);
    *reinterpret_cast<ushort4*>(&p[row * 2048 + tid * 8])     = o0;
    *reinterpret_cast<ushort4*>(&p[row * 2048 + tid * 8 + 4]) = o1;
}

extern "C" void kernel_launch(void* const* d_in, const int* in_sizes, int n_in,
                              void* d_out, int out_size, void* d_ws, size_t ws_size,
                              hipStream_t stream)
{
    (void)in_sizes; (void)n_in; (void)out_size; (void)ws_size;

    const int S = 2048, D = 1024;
    const long long BS  = 8LL * S;          // 16384
    const long long SD  = (long long)S * D;
    const long long SS  = (long long)S * S;
    const long long BSD = BS * D;
    const long long DD  = (long long)D * D;

    const float* x    = (const float*)d_in[0];
    const int*   mask = (const int*)d_in[1];
    const float* wq   = (const float*)d_in[2];
    const float* wk   = (const float*)d_in[3];
    const float* wv   = (const float*)d_in[4];

    float* out = (float*)d_out;             // [BS, D] f32 (final)
    float* s   = out + BSD;                 // [B, S, S] f32 (final)

    // ws layout (halves):
    //   G [16384][1024] | (free BSD)        <- later p [B][S][S] = 2*BSD halves
    //   Vt [B][D][S] | MtWv [2048][1024] (Mt rows 0-1023, wv rows 1024-2047)
    unsigned short* G    = (unsigned short*)d_ws;
    unsigned short* p    = G;               // overwrites G + free
    unsigned short* Vt   = G + 2 * BSD;
    unsigned short* MtWv = G + 3 * BSD;
    unsigned short* Mth  = MtWv;
    unsigned short* wvh  = MtWv + DD;

    // xh lives in d_out's out-region until PV overwrites it
    unsigned short* xh = (unsigned short*)out;
    // transposed weight splits live in d_out's s-region until scores overwrites it
    unsigned short* wqTh = (unsigned short*)s;   // [1024][1024] = wq^T hi
    unsigned short* wqTl = wqTh + DD;
    unsigned short* wkTh = wqTl + DD;
    unsigned short* wkTl = wkTh + DD;

    dim3 blk256(256), blk512(512);

    cvt_kernel<<<dim3(4096), blk256, 0, stream>>>(x, xh, BSD);
    tsplit_kernel<<<dim3(16, 16), blk256, 0, stream>>>(wq, wqTh, wqTl, D);
    tsplit_kernel<<<dim3(16, 16), blk256, 0, stream>>>(wk, wkTh, wkTl, D);
    cvt_kernel<<<dim3(512), blk256, 0, stream>>>(wv, wvh, DD);

    // Mt[j][i] = sum_e wk[e][j]*wq[e][i]; A = (wkTh,wkTl) split, B = wqTh, f16 out
    gemm2<<<dim3(8, 4, 1), blk512, 0, stream>>>(
        wkTh, wkTl, D, wqTh, D, Mth, D, D);

    // Fused [G | V^T] = xh @ [Mt | wv]^T  (1-term, N=2048, mixed epilogue)
    mfma_gemm1<4><<<dim3(64, 8, 1), blk512, 0, stream>>>(
        xh, 0, D, MtWv, 0, D,
        nullptr, G, Vt, 0, D, D, nullptr, 0);

    // scores = G @ xh^T + NEG_INF*mask  (1-term, f32 out)
    mfma_gemm1<0><<<dim3(8, 8, 8), blk512, 0, stream>>>(
        G, SD, D, xh, SD, D,
        s, nullptr, nullptr, SS, S, D, mask, S);

    // softmax in place + f16 p for PV (p overwrites G)
    softmax_kernel<<<dim3(16384), blk256, 0, stream>>>(s, p);

    // out = p @ V = p @ (V^T)^T  (f32 out)
    mfma_gemm1<0><<<dim3(8, 4, 8), blk512, 0, stream>>>(
        p, SS, S, Vt, SD, S, out, nullptr, nullptr, SD, D, S, nullptr, 0);
}